// Round 8
// baseline (470.507 us; speedup 1.0000x reference)
//
#include <hip/hip_runtime.h>
#include <hip/hip_bf16.h>
#include <stdint.h>

#define N_NODES   50000
#define N_EDGES   800000
#define D_MODEL   64
#define D_HIDDEN  256
#define N_GRAPHS  64
#define EPS_GN    1e-5f

#define NBINS_PAD 50176            // 196 * 256, zero-padded histogram
#define NB_SCAN   196

typedef __attribute__((ext_vector_type(8))) short short8;   // 8 bf16 (4 VGPRs)
typedef __attribute__((ext_vector_type(4))) float f32x4;
typedef __attribute__((ext_vector_type(4))) float float4v;
typedef __attribute__((ext_vector_type(2))) unsigned int uint2v;
typedef __attribute__((ext_vector_type(4))) unsigned int uint4v;

static __device__ __forceinline__ short f2bf(float f) {
  union { float f; uint32_t u; } v; v.f = f;
  uint32_t r = (v.u + 0x7fffu + ((v.u >> 16) & 1u)) >> 16;   // RNE
  return (short)(uint16_t)r;
}

// pack two fp32 -> bf16x2 (RNE), hi16 extraction fused via v_perm_b32
static __device__ __forceinline__ uint32_t pack_bf16x2(float lo, float hi) {
  union { float f; uint32_t u; } a, b;
  a.f = lo; b.f = hi;
  uint32_t ra = a.u + 0x7fffu + ((a.u >> 16) & 1u);
  uint32_t rb = b.u + 0x7fffu + ((b.u >> 16) & 1u);
  return __builtin_amdgcn_perm(rb, ra, 0x07060302u);  // {rb.b3,rb.b2,ra.b3,ra.b2}
}

// hw packed cvt: dst[15:0]=bf16(lo), dst[31:16]=bf16(hi)  (RNE in default mode)
static __device__ __forceinline__ uint32_t cvt_pk_bf16(float lo, float hi) {
  uint32_t r;
  asm("v_cvt_pk_bf16_f32 %0, %1, %2" : "=v"(r) : "v"(lo), "v"(hi));
  return r;
}

// fast silu: hardware rcp (rel err ~2^-22 << bf16 rounding) instead of IEEE div
static __device__ __forceinline__ float silu_f(float x) {
  return x * __builtin_amdgcn_rcpf(1.0f + __expf(-x));
}

static __device__ __forceinline__ f32x4 mfma16(short8 a, short8 b, f32x4 c) {
  return __builtin_amdgcn_mfma_f32_16x16x32_bf16(a, b, c, 0, 0, 0);
}

// ---------------------------------------------------------------------------
// Weight prep (4 mats -> MFMA B-frag layout) + hist zero + h -> bf16 copy.
// B-frag: [kt][nt][lane][8]; elem j of lane L = w[kt*32+(L>>4)*8+j][nt*16+(L&15)]
// For the K=256 matrices (w2/u2) the K dimension is PERMUTED: storage index kk
// holds logical hidden unit ((kk>>6)*4+(kk&3))*16+((kk>>2)&15), matching the
// packed epilogue-1 sH layout (ns = wave*64 + col*4 + nt).
// ---------------------------------------------------------------------------
#define HBF_BLOCKS 1563   // ceil(50000*64/8/256)

__global__ void prep_all(const float* __restrict__ mw1, const float* __restrict__ mw2,
                         const float* __restrict__ uw1, const float* __restrict__ uw2,
                         const float* __restrict__ h,
                         short* __restrict__ w1f, short* __restrict__ w2f,
                         short* __restrict__ u1f, short* __restrict__ u2f,
                         short* __restrict__ h_bf, int* __restrict__ hist) {
  int b = blockIdx.x;
  if (b >= 52 && b < 248) {            // zero histogram (196*256 = 50176 ints)
    hist[(b - 52) * 256 + threadIdx.x] = 0;
    return;
  }
  if (b >= 248) {                      // h -> bf16, 8 elems/thread
    int t2 = (b - 248) * 256 + threadIdx.x;
    if (t2 < N_NODES * D_MODEL / 8) {
      const float4v* src = (const float4v*)(h + (size_t)t2 * 8);
      float4v v0 = src[0], v1 = src[1];
      uint4v p = {pack_bf16x2(v0.x, v0.y), pack_bf16x2(v0.z, v0.w),
                  pack_bf16x2(v1.x, v1.y), pack_bf16x2(v1.z, v1.w)};
      *(uint4v*)(h_bf + (size_t)t2 * 8) = p;
    }
    return;
  }
  const float* w; short* out; int K, Nn, t;
  if (b < 20)      { w = mw1; out = w1f; K = 160; Nn = 256; t = b * 256 + threadIdx.x; }
  else if (b < 28) { w = mw2; out = w2f; K = 256; Nn = 64;  t = (b - 20) * 256 + threadIdx.x; }
  else if (b < 44) { w = uw1; out = u1f; K = 128; Nn = 256; t = (b - 28) * 256 + threadIdx.x; }
  else             { w = uw2; out = u2f; K = 256; Nn = 64;  t = (b - 44) * 256 + threadIdx.x; }
  int total = (K >> 5) * (Nn >> 4) * 64;
  if (t >= total) return;
  const bool permK = (K == 256);       // w2/u2: K side carries the hidden perm
  int lane = t & 63;
  int rest = t >> 6;
  int ntN = Nn >> 4;
  int nt = rest % ntN;
  int kt = rest / ntN;
  int n  = nt * 16 + (lane & 15);
  int k0 = kt * 32 + (lane >> 4) * 8;
  short* o = out + (size_t)t * 8;
#pragma unroll
  for (int j = 0; j < 8; ++j) {
    int kk = k0 + j;
    int kr = permK ? ((kk >> 6) * 4 + (kk & 3)) * 16 + ((kk >> 2) & 15) : kk;
    o[j] = f2bf(w[(size_t)kr * Nn + n]);
  }
}

// ---------------------------------------------------------------------------
// Counting sort of edges by dst: hist -> 2-level exclusive scan -> scatter.
// scan3 folded into scatter; agg zero folded into hist_k; s1/s2/cnt zero
// folded into scan2.
// ---------------------------------------------------------------------------
__global__ __launch_bounds__(256)
void hist_k(const int* __restrict__ ei, int* __restrict__ hist,
            float* __restrict__ agg) {
  int e = blockIdx.x * 256 + threadIdx.x;
  if (e >= N_EDGES) return;
  *(float4v*)(agg + (size_t)e * 4) = (float4v){0.f, 0.f, 0.f, 0.f};  // 3.2M floats
  atomicAdd(&hist[ei[N_EDGES + e]], 1);
}

__global__ __launch_bounds__(256)
void scan1(const int* __restrict__ hist, int* __restrict__ offs,
           int* __restrict__ bsums) {
  __shared__ int tmp[256];
  int i = blockIdx.x * 256 + threadIdx.x;
  int v = hist[i];
  tmp[threadIdx.x] = v;
  __syncthreads();
#pragma unroll
  for (int d = 1; d < 256; d <<= 1) {
    int t = (threadIdx.x >= d) ? tmp[threadIdx.x - d] : 0;
    __syncthreads();
    tmp[threadIdx.x] += t;
    __syncthreads();
  }
  offs[i] = tmp[threadIdx.x] - v;                 // exclusive within block
  if (threadIdx.x == 255) bsums[blockIdx.x] = tmp[255];
}

__global__ __launch_bounds__(256)
void scan2(const int* __restrict__ bsums, int* __restrict__ bpre,
           float* __restrict__ zstats) {
  // zero s1|s2|cnt (contiguous 8256 floats) — consumed by node_mlp later
  for (int i = threadIdx.x; i < 8256; i += 256) zstats[i] = 0.f;
  __shared__ int tmp[256];
  int v = (threadIdx.x < NB_SCAN) ? bsums[threadIdx.x] : 0;
  tmp[threadIdx.x] = v;
  __syncthreads();
#pragma unroll
  for (int d = 1; d < 256; d <<= 1) {
    int t = (threadIdx.x >= d) ? tmp[threadIdx.x - d] : 0;
    __syncthreads();
    tmp[threadIdx.x] += t;
    __syncthreads();
  }
  bpre[threadIdx.x] = tmp[threadIdx.x] - v;       // exclusive block prefix
}

__global__ __launch_bounds__(256)
void scatter_k(const int* __restrict__ ei, int* __restrict__ offs,
               const int* __restrict__ bpre, int* __restrict__ sorted) {
  int e = blockIdx.x * 256 + threadIdx.x;
  if (e >= N_EDGES) return;
  int d = ei[N_EDGES + e];
  int pos = atomicAdd(&offs[d], 1) + bpre[d >> 8];
  sorted[pos] = e;
}

// ---------------------------------------------------------------------------
// Edge MLP — block-cooperative, 64 dst-sorted edges / block.
// R14 = R13 + BLOCK-level run-reduce: wave 0 alone scans all 64 sC rows after
// b4 (dst-sorted across whole block) -> ~5 runs/block vs ~8 (per-wave) ->
// atomics 6.4M -> ~4M. Tests the L2-atomic-serialization hypothesis (R11:
// +30% occupancy gave 0% -> stall is occupancy-insensitive shared resource).
// + bf2[0] hoisted above epilogue-1 (L2 latency hidden under silu phase).
// ---------------------------------------------------------------------------
#define LDA_E 168   // 160 + 8 pad shorts; row = 336 B (16B aligned)
#define LDH   264   // 256 + 8 pad shorts; row = 528 B (16B aligned)
#define LDC   68    // fp32 stride of C tile

__global__ __launch_bounds__(256, 2)
void edge_mlp(const short* __restrict__ h_bf, const float* __restrict__ ea,
              const int* __restrict__ ei, const int* __restrict__ sorted,
              const short* __restrict__ w1f, const float* __restrict__ b1,
              const short* __restrict__ w2f, const float* __restrict__ b2,
              float* __restrict__ agg) {
  __shared__ __align__(16) short buf[64 * LDH];    // sA [64][LDA_E] then sH
  __shared__ __align__(16) float sC[64 * LDC];     // 17408 B
  __shared__ int s_ids[4][48];                     // src[16], dst[16], eid[16]

  const int tid  = threadIdx.x;
  const int lane = tid & 63;
  const int wave = tid >> 6;
  const int col  = lane & 15;
  const int quad = lane >> 4;
  const int eb   = blockIdx.x * 64 + wave * 16;    // this wave's 16 sorted slots
  short* sA = buf;
  short* sH = buf;

  // ---- resolve sorted edge ids -> src/dst/eid (wave-local)
  if (lane < 48) {
    int i15 = lane & 15;
    int e0 = sorted[eb + i15];
    int v;
    if (lane < 16)      v = ei[e0];
    else if (lane < 32) v = ei[N_EDGES + e0];
    else                v = e0;
    s_ids[wave][lane] = v;
  }

  // ---- stage h_dst | h_src rows (bf16 copy, no conversion)
#pragma unroll
  for (int it = 0; it < 2; ++it) {
    int idx = it * 64 + lane;        // 0..127
    int e = idx >> 3, c = idx & 7;
    int row = wave * 16 + e;
    int d = s_ids[wave][16 + e];
    int s = s_ids[wave][e];
    *(short8*)&sA[row * LDA_E + c * 8] =
        *(const short8*)(h_bf + (size_t)d * D_MODEL + c * 8);
    *(short8*)&sA[row * LDA_E + 64 + c * 8] =
        *(const short8*)(h_bf + (size_t)s * D_MODEL + c * 8);
  }
  // ---- stage edge_attr (fp32 -> packed bf16)
#pragma unroll
  for (int it = 0; it < 2; ++it) {
    int idx = it * 64 + lane;        // 0..127
    int e = idx >> 3, j = idx & 7;
    int row = wave * 16 + e;
    int eid = s_ids[wave][32 + e];
    float4v v = *(const float4v*)(ea + (size_t)eid * 32 + j * 4);
    uint2v p = {pack_bf16x2(v.x, v.y), pack_bf16x2(v.z, v.w)};
    *(uint2v*)&sA[row * LDA_E + 128 + j * 4] = p;
  }
  __syncthreads();                                  // b1: sA visible

  // ---- GEMM1: [64,160] x [160,256]; wave covers n-tiles [4w, 4w+4)
  f32x4 acc[4][4];
#pragma unroll
  for (int mt = 0; mt < 4; ++mt)
#pragma unroll
    for (int nt = 0; nt < 4; ++nt)
      acc[mt][nt] = (f32x4){0.f, 0.f, 0.f, 0.f};

  short8 bf[2][4];
#pragma unroll
  for (int nt = 0; nt < 4; ++nt)
    bf[0][nt] = *(const short8*)(w1f + (size_t)((wave * 4 + nt) * 64 + lane) * 8);

#pragma unroll
  for (int kt = 0; kt < 5; ++kt) {
    if (kt < 4) {
#pragma unroll
      for (int nt = 0; nt < 4; ++nt)
        bf[(kt + 1) & 1][nt] = *(const short8*)(
            w1f + (size_t)(((kt + 1) * 16 + wave * 4 + nt) * 64 + lane) * 8);
    }
    short8 af[4];
#pragma unroll
    for (int mt = 0; mt < 4; ++mt)
      af[mt] = *(const short8*)&sA[(mt * 16 + col) * LDA_E + kt * 32 + quad * 8];
    __builtin_amdgcn_s_setprio(1);
#pragma unroll
    for (int nt = 0; nt < 4; ++nt)
#pragma unroll
      for (int mt = 0; mt < 4; ++mt)
        acc[mt][nt] = mfma16(af[mt], bf[kt & 1][nt], acc[mt][nt]);
    __builtin_amdgcn_s_setprio(0);
  }

  // ---- hoist GEMM2's first weight fragment (L2 latency hides under silu)
  short8 bf2[2];
  bf2[0] = *(const short8*)(w2f + (size_t)(wave * 64 + lane) * 8);

  __syncthreads();                                  // b2: sA dead, safe to reuse

  // ---- bias + silu -> sH, permuted-hidden packed writes:
  // storage col ns = wave*64 + col*4 + nt  (4 consecutive shorts per lane)
  {
    float b1v[4];
#pragma unroll
    for (int nt = 0; nt < 4; ++nt) b1v[nt] = b1[(wave * 4 + nt) * 16 + col];
#pragma unroll
    for (int mt = 0; mt < 4; ++mt) {
#pragma unroll
      for (int r = 0; r < 4; ++r) {
        const int row = mt * 16 + quad * 4 + r;
        float v0 = silu_f(acc[mt][0][r] + b1v[0]);
        float v1 = silu_f(acc[mt][1][r] + b1v[1]);
        float v2 = silu_f(acc[mt][2][r] + b1v[2]);
        float v3 = silu_f(acc[mt][3][r] + b1v[3]);
        uint2v p = {cvt_pk_bf16(v0, v1), cvt_pk_bf16(v2, v3)};
        *(uint2v*)&sH[row * LDH + wave * 64 + col * 4] = p;
      }
    }
  }
  __syncthreads();                                  // b3: sH visible

  // ---- GEMM2: [64,256] x [256,64]; wave covers n-tile `wave` (16 cols)
  f32x4 acc2[4];
#pragma unroll
  for (int mt = 0; mt < 4; ++mt) acc2[mt] = (f32x4){0.f, 0.f, 0.f, 0.f};

#pragma unroll
  for (int kt = 0; kt < 8; ++kt) {
    if (kt < 7)
      bf2[(kt + 1) & 1] = *(const short8*)(
          w2f + (size_t)(((kt + 1) * 4 + wave) * 64 + lane) * 8);
    short8 af[4];
#pragma unroll
    for (int mt = 0; mt < 4; ++mt)
      af[mt] = *(const short8*)&sH[(mt * 16 + col) * LDH + kt * 32 + quad * 8];
    __builtin_amdgcn_s_setprio(1);
#pragma unroll
    for (int mt = 0; mt < 4; ++mt)
      acc2[mt] = mfma16(af[mt], bf2[kt & 1], acc2[mt]);
    __builtin_amdgcn_s_setprio(0);
  }

  // ---- dump C (+bias) into separate sC tile (no barrier needed before)
  {
    const int n = wave * 16 + col;
    const float bias = b2[n];
#pragma unroll
    for (int mt = 0; mt < 4; ++mt)
#pragma unroll
      for (int r = 0; r < 4; ++r)
        sC[(mt * 16 + quad * 4 + r) * LDC + n] = acc2[mt][r] + bias;
  }
  __syncthreads();                                  // b4: sC visible

  // ---- BLOCK-level run-reduce (wave 0 only): all 64 rows are dst-sorted
  // across the block -> one atomic per block-level run per feature.
  if (wave == 0) {
    float sum = 0.f;
    int prev = s_ids[0][16];
#pragma unroll 8
    for (int r = 0; r < 64; ++r) {
      float v = sC[r * LDC + lane];
      int d = s_ids[r >> 4][16 + (r & 15)];   // LDS broadcast -> wave-uniform
      if (d != prev) {
        atomicAdd(agg + (size_t)prev * D_MODEL + lane, sum);
        sum = 0.f; prev = d;
      }
      sum += v;
    }
    atomicAdd(agg + (size_t)prev * D_MODEL + lane, sum);
  }
}

// ---------------------------------------------------------------------------
// Node MLP — block-cooperative, 64 nodes / block, fused GraphNorm stats.
// R14: uniform-graph fast path (~92% of blocks): shfl_xor combines the 4
// quads -> one s1/s2 atomic per feature per block (4x fewer atomics on the
// hot 8K-address stats region). + bf2[0] hoist.
// ---------------------------------------------------------------------------
#define LDA_N 136   // 128 + 8 pad shorts; row = 272 B (16B aligned)

__global__ __launch_bounds__(256, 2)
void node_mlp(const float* __restrict__ h, const short* __restrict__ h_bf,
              const float* __restrict__ agg,
              const short* __restrict__ w1f, const float* __restrict__ b1,
              const short* __restrict__ w2f, const float* __restrict__ b2,
              const int* __restrict__ batch,
              float* __restrict__ hnew,
              float* __restrict__ s1, float* __restrict__ s2,
              float* __restrict__ cnt) {
  __shared__ __align__(16) short buf[64 * LDH];    // sA [64][LDA_N] then sH
  __shared__ int s_b[64];                          // batch ids of block rows

  const int tid  = threadIdx.x;
  const int lane = tid & 63;
  const int wave = tid >> 6;
  const int col  = lane & 15;
  const int quad = lane >> 4;
  const int nb   = blockIdx.x * 64;
  short* sA = buf;
  short* sH = buf;

  if (tid < 64) {
    int gi = nb + tid;
    s_b[tid] = batch[(gi < N_NODES) ? gi : (N_NODES - 1)];
  }

  // ---- stage h rows (bf16 copy)
#pragma unroll
  for (int it = 0; it < 2; ++it) {
    int idx = it * 64 + lane;     // 0..127
    int i = idx >> 3, c = idx & 7;
    int row = wave * 16 + i;
    int gi = nb + row;
    if (gi >= N_NODES) gi = N_NODES - 1;
    *(short8*)&sA[row * LDA_N + c * 8] =
        *(const short8*)(h_bf + (size_t)gi * D_MODEL + c * 8);
  }
  // ---- stage agg rows (fp32 -> packed bf16)
#pragma unroll
  for (int it = 0; it < 4; ++it) {
    int idx = it * 64 + lane;     // 0..255
    int i = idx >> 4, j = idx & 15;
    int row = wave * 16 + i;
    int gi = nb + row;
    if (gi >= N_NODES) gi = N_NODES - 1;
    float4v v = *(const float4v*)(agg + (size_t)gi * D_MODEL + j * 4);
    uint2v p = {pack_bf16x2(v.x, v.y), pack_bf16x2(v.z, v.w)};
    *(uint2v*)&sA[row * LDA_N + 64 + j * 4] = p;
  }
  __syncthreads();                                  // b1

  // ---- per-graph node counts (one wave; ballot run-length over 64 rows)
  if (wave == 3) {
    int gi = nb + lane;
    bool valid = gi < N_NODES;
    int g = s_b[lane];
    int gp = __shfl_up(g, 1);
    bool start = valid && (lane == 0 || g != gp);
    unsigned long long bmask = __ballot(start);
    unsigned long long imask = __ballot(!valid);
    if (start) {
      unsigned long long higher =
          (lane == 63) ? 0ULL : (((bmask | imask) >> (lane + 1)) << (lane + 1));
      int next = higher ? (__ffsll((long long)higher) - 1) : 64;
      atomicAdd(&cnt[g], (float)(next - lane));
    }
  }

  // ---- GEMM1: K=128; wave covers n-tiles [4w, 4w+4)
  f32x4 acc[4][4];
#pragma unroll
  for (int mt = 0; mt < 4; ++mt)
#pragma unroll
    for (int nt = 0; nt < 4; ++nt)
      acc[mt][nt] = (f32x4){0.f, 0.f, 0.f, 0.f};

  short8 bf[2][4];
#pragma unroll
  for (int nt = 0; nt < 4; ++nt)
    bf[0][nt] = *(const short8*)(w1f + (size_t)((wave * 4 + nt) * 64 + lane) * 8);

#pragma unroll
  for (int kt = 0; kt < 4; ++kt) {
    if (kt < 3) {
#pragma unroll
      for (int nt = 0; nt < 4; ++nt)
        bf[(kt + 1) & 1][nt] = *(const short8*)(
            w1f + (size_t)(((kt + 1) * 16 + wave * 4 + nt) * 64 + lane) * 8);
    }
    short8 af[4];
#pragma unroll
    for (int mt = 0; mt < 4; ++mt)
      af[mt] = *(const short8*)&sA[(mt * 16 + col) * LDA_N + kt * 32 + quad * 8];
    __builtin_amdgcn_s_setprio(1);
#pragma unroll
    for (int nt = 0; nt < 4; ++nt)
#pragma unroll
      for (int mt = 0; mt < 4; ++mt)
        acc[mt][nt] = mfma16(af[mt], bf[kt & 1][nt], acc[mt][nt]);
    __builtin_amdgcn_s_setprio(0);
  }

  // ---- hoist GEMM2's first weight fragment
  short8 bf2[2];
  bf2[0] = *(const short8*)(w2f + (size_t)(wave * 64 + lane) * 8);

  __syncthreads();                                  // b2: sA dead

  // ---- bias + silu -> sH, permuted-hidden packed writes (matches u2f perm)
  {
    float b1v[4];
#pragma unroll
    for (int nt = 0; nt < 4; ++nt) b1v[nt] = b1[(wave * 4 + nt) * 16 + col];
#pragma unroll
    for (int mt = 0; mt < 4; ++mt) {
#pragma unroll
      for (int r = 0; r < 4; ++r) {
        const int row = mt * 16 + quad * 4 + r;
        float v0 = silu_f(acc[mt][0][r] + b1v[0]);
        float v1 = silu_f(acc[mt][1][r] + b1v[1]);
        float v2 = silu_f(acc[mt][2][r] + b1v[2]);
        float v3 = silu_f(acc[mt][3][r] + b1v[3]);
        uint2v p = {cvt_pk_bf16(v0, v1), cvt_pk_bf16(v2, v3)};
        *(uint2v*)&sH[row * LDH + wave * 64 + col * 4] = p;
      }
    }
  }
  __syncthreads();                                  // b3: sH visible

  // ---- GEMM2: K=256; wave covers n-tile `wave`
  f32x4 acc2[4];
#pragma unroll
  for (int mt = 0; mt < 4; ++mt) acc2[mt] = (f32x4){0.f, 0.f, 0.f, 0.f};

#pragma unroll
  for (int kt = 0; kt < 8; ++kt) {
    if (kt < 7)
      bf2[(kt + 1) & 1] = *(const short8*)(
          w2f + (size_t)(((kt + 1) * 4 + wave) * 64 + lane) * 8);
    short8 af[4];
#pragma unroll
    for (int mt = 0; mt < 4; ++mt)
      af[mt] = *(const short8*)&sH[(mt * 16 + col) * LDH + kt * 32 + quad * 8];
    __builtin_amdgcn_s_setprio(1);
#pragma unroll
    for (int mt = 0; mt < 4; ++mt)
      acc2[mt] = mfma16(af[mt], bf2[kt & 1], acc2[mt]);
    __builtin_amdgcn_s_setprio(0);
  }

  // ---- epilogue: h_new = h + dh -> global + GraphNorm stat accumulation.
  {
    const int n = wave * 16 + col;
    const float bias = b2[n];
    const bool uni = (nb + 64 <= N_NODES) && (s_b[0] == s_b[63]);
    if (uni) {
      // fast path (~92% of blocks): whole block one graph, all rows valid
      const int g = s_b[0];
      float a1 = 0.f, a2 = 0.f;
#pragma unroll
      for (int mt = 0; mt < 4; ++mt) {
#pragma unroll
        for (int r = 0; r < 4; ++r) {
          const int gi = nb + mt * 16 + quad * 4 + r;
          float hv = h[(size_t)gi * D_MODEL + n] + acc2[mt][r] + bias;
          hnew[(size_t)gi * D_MODEL + n] = hv;
          a1 += hv; a2 += hv * hv;
        }
      }
      a1 += __shfl_xor(a1, 16); a1 += __shfl_xor(a1, 32);
      a2 += __shfl_xor(a2, 16); a2 += __shfl_xor(a2, 32);
      if (quad == 0) {
        atomicAdd(&s1[g * D_MODEL + n], a1);
        atomicAdd(&s2[g * D_MODEL + n], a2);
      }
    } else {
      float a1 = 0.f, a2 = 0.f;
      int prev = s_b[quad * 4];     // lane's first row (mt=0, r=0)
#pragma unroll
      for (int mt = 0; mt < 4; ++mt) {
#pragma unroll
        for (int r = 0; r < 4; ++r) {
          const int row = mt * 16 + quad * 4 + r;
          const int gi = nb + row;
          const bool valid = gi < N_NODES;
          int g = s_b[row];
          if (g != prev) {
            atomicAdd(&s1[prev * D_MODEL + n], a1);
            atomicAdd(&s2[prev * D_MODEL + n], a2);
            a1 = 0.f; a2 = 0.f; prev = g;
          }
          if (valid) {
            float hv = h[(size_t)gi * D_MODEL + n] + acc2[mt][r] + bias;
            hnew[(size_t)gi * D_MODEL + n] = hv;
            a1 += hv; a2 += hv * hv;
          }
        }
      }
      atomicAdd(&s1[prev * D_MODEL + n], a1);
      atomicAdd(&s2[prev * D_MODEL + n], a2);
    }
  }
}

// ---------------------------------------------------------------------------
// GraphNorm normalize (stats already produced by node_mlp).
// ---------------------------------------------------------------------------
__global__ __launch_bounds__(256)
void gn_norm(float* __restrict__ x, const int* __restrict__ batch,
             const float* __restrict__ s1, const float* __restrict__ s2,
             const float* __restrict__ cnt, const float* __restrict__ alpha,
             const float* __restrict__ weight, const float* __restrict__ bias) {
  int idx = blockIdx.x * 256 + threadIdx.x;
  if (idx >= N_NODES * D_MODEL) return;
  int i = idx >> 6, f = idx & 63;
  int g = batch[i];
  float c = fmaxf(cnt[g], 1.f);
  float m   = s1[g * D_MODEL + f] / c;
  float ex2 = s2[g * D_MODEL + f] / c;
  float a = alpha[f];
  float var = ex2 - 2.f * a * m * m + a * a * m * m;
  float hc = x[idx] - a * m;
  x[idx] = weight[f] * hc * rsqrtf(var + EPS_GN) + bias[f];
}

// ---------------------------------------------------------------------------
extern "C" void kernel_launch(void* const* d_in, const int* in_sizes, int n_in,
                              void* d_out, int out_size, void* d_ws, size_t ws_size,
                              hipStream_t stream) {
  const float* h     = (const float*)d_in[0];
  const float* ea    = (const float*)d_in[1];
  const int*   ei    = (const int*)d_in[2];   // [2][E], row0=src, row1=dst
  const int*   batch = (const int*)d_in[3];
  const float* mw1   = (const float*)d_in[4];
  const float* mb1   = (const float*)d_in[5];
  const float* mw2   = (const float*)d_in[6];
  const float* mb2   = (const float*)d_in[7];
  const float* uw1   = (const float*)d_in[8];
  const float* ub1   = (const float*)d_in[9];
  const float* uw2   = (const float*)d_in[10];
  const float* ub2   = (const float*)d_in[11];
  const float* gw    = (const float*)d_in[12];
  const float* gb    = (const float*)d_in[13];
  const float* ga    = (const float*)d_in[14];

  char* ws = (char*)d_ws;
  float* agg    = (float*)(ws + 0);             // 12,800,000 B
  short* w1f    = (short*)(ws + 12800000);      //     81,920 B
  short* w2f    = (short*)(ws + 12881920);      //     32,768 B
  short* u1f    = (short*)(ws + 12914688);      //     65,536 B
  short* u2f    = (short*)(ws + 12980224);      //     32,768 B
  float* s1     = (float*)(ws + 13012992);      //     16,384 B
  float* s2     = (float*)(ws + 13029376);      //     16,384 B
  float* cnt    = (float*)(ws + 13045760);      //        256 B
  int*   hist   = (int*)  (ws + 13046016);      //    200,704 B (50176 ints)
  int*   offs   = (int*)  (ws + 13246720);      //    200,704 B
  int*   bsums  = (int*)  (ws + 13447424);      //      1,024 B
  int*   bpre   = (int*)  (ws + 13448448);      //      1,024 B
  int*   sorted = (int*)  (ws + 13449472);      //  3,200,000 B
  short* h_bf   = (short*)(ws + 16649472);      //  6,400,000 B -> end 23,049,472

  float* zstats = (float*)(ws + 13012992);      // s1|s2|cnt contiguous (8256 f)

  // weights (52) + hist-zero (196) + h_bf (1563)
  prep_all<<<52 + 196 + HBF_BLOCKS, 256, 0, stream>>>(mw1, mw2, uw1, uw2, h,
                                                      w1f, w2f, u1f, u2f,
                                                      h_bf, hist);

  // counting sort of edges by dst (hist_k also zeroes agg)
  hist_k  <<<(N_EDGES + 255) / 256, 256, 0, stream>>>(ei, hist, agg);
  scan1   <<<NB_SCAN, 256, 0, stream>>>(hist, offs, bsums);
  scan2   <<<1, 256, 0, stream>>>(bsums, bpre, zstats);
  scatter_k<<<(N_EDGES + 255) / 256, 256, 0, stream>>>(ei, offs, bpre, sorted);

  edge_mlp<<<N_EDGES / 64, 256, 0, stream>>>(h_bf, ea, ei, sorted,
                                             w1f, mb1, w2f, mb2, agg);

  node_mlp<<<(N_NODES + 63) / 64, 256, 0, stream>>>(h, h_bf, agg,
                                                    u1f, ub1, u2f, ub2,
                                                    batch, (float*)d_out,
                                                    s1, s2, cnt);

  gn_norm<<<(N_NODES * D_MODEL + 255) / 256, 256, 0, stream>>>(
      (float*)d_out, batch, s1, s2, cnt, ga, gw, gb);
}

// Round 9
// 467.670 us; speedup vs baseline: 1.0061x; 1.0061x over previous
//
#include <hip/hip_runtime.h>
#include <hip/hip_bf16.h>
#include <stdint.h>

#define N_NODES   50000
#define N_EDGES   800000
#define D_MODEL   64
#define D_HIDDEN  256
#define N_GRAPHS  64
#define EPS_GN    1e-5f

#define NBINS_PAD 50176            // 196 * 256, zero-padded histogram
#define NB_SCAN   196

typedef __attribute__((ext_vector_type(8))) short short8;   // 8 bf16 (4 VGPRs)
typedef __attribute__((ext_vector_type(4))) float f32x4;
typedef __attribute__((ext_vector_type(4))) float float4v;
typedef __attribute__((ext_vector_type(2))) unsigned int uint2v;
typedef __attribute__((ext_vector_type(4))) unsigned int uint4v;

static __device__ __forceinline__ short f2bf(float f) {
  union { float f; uint32_t u; } v; v.f = f;
  uint32_t r = (v.u + 0x7fffu + ((v.u >> 16) & 1u)) >> 16;   // RNE
  return (short)(uint16_t)r;
}

// pack two fp32 -> bf16x2 (RNE), hi16 extraction fused via v_perm_b32
static __device__ __forceinline__ uint32_t pack_bf16x2(float lo, float hi) {
  union { float f; uint32_t u; } a, b;
  a.f = lo; b.f = hi;
  uint32_t ra = a.u + 0x7fffu + ((a.u >> 16) & 1u);
  uint32_t rb = b.u + 0x7fffu + ((b.u >> 16) & 1u);
  return __builtin_amdgcn_perm(rb, ra, 0x07060302u);  // {rb.b3,rb.b2,ra.b3,ra.b2}
}

// hw packed cvt: dst[15:0]=bf16(lo), dst[31:16]=bf16(hi)  (RNE in default mode)
static __device__ __forceinline__ uint32_t cvt_pk_bf16(float lo, float hi) {
  uint32_t r;
  asm("v_cvt_pk_bf16_f32 %0, %1, %2" : "=v"(r) : "v"(lo), "v"(hi));
  return r;
}

// fast silu: hardware rcp (rel err ~2^-22 << bf16 rounding) instead of IEEE div
static __device__ __forceinline__ float silu_f(float x) {
  return x * __builtin_amdgcn_rcpf(1.0f + __expf(-x));
}

static __device__ __forceinline__ f32x4 mfma16(short8 a, short8 b, f32x4 c) {
  return __builtin_amdgcn_mfma_f32_16x16x32_bf16(a, b, c, 0, 0, 0);
}

// ---------------------------------------------------------------------------
// Weight prep (4 mats -> MFMA B-frag layout) + hist zero + h -> bf16 copy.
// B-frag: [kt][nt][lane][8]; elem j of lane L = w[kt*32+(L>>4)*8+j][nt*16+(L&15)]
// For the K=256 matrices (w2/u2) the K dimension is PERMUTED: storage index kk
// holds logical hidden unit ((kk>>6)*4+(kk&3))*16+((kk>>2)&15), matching the
// packed epilogue-1 sH layout (ns = wave*64 + col*4 + nt).
// ---------------------------------------------------------------------------
#define HBF_BLOCKS 1563   // ceil(50000*64/8/256)

__global__ void prep_all(const float* __restrict__ mw1, const float* __restrict__ mw2,
                         const float* __restrict__ uw1, const float* __restrict__ uw2,
                         const float* __restrict__ h,
                         short* __restrict__ w1f, short* __restrict__ w2f,
                         short* __restrict__ u1f, short* __restrict__ u2f,
                         short* __restrict__ h_bf, int* __restrict__ hist) {
  int b = blockIdx.x;
  if (b >= 52 && b < 248) {            // zero histogram (196*256 = 50176 ints)
    hist[(b - 52) * 256 + threadIdx.x] = 0;
    return;
  }
  if (b >= 248) {                      // h -> bf16, 8 elems/thread
    int t2 = (b - 248) * 256 + threadIdx.x;
    if (t2 < N_NODES * D_MODEL / 8) {
      const float4v* src = (const float4v*)(h + (size_t)t2 * 8);
      float4v v0 = src[0], v1 = src[1];
      uint4v p = {pack_bf16x2(v0.x, v0.y), pack_bf16x2(v0.z, v0.w),
                  pack_bf16x2(v1.x, v1.y), pack_bf16x2(v1.z, v1.w)};
      *(uint4v*)(h_bf + (size_t)t2 * 8) = p;
    }
    return;
  }
  const float* w; short* out; int K, Nn, t;
  if (b < 20)      { w = mw1; out = w1f; K = 160; Nn = 256; t = b * 256 + threadIdx.x; }
  else if (b < 28) { w = mw2; out = w2f; K = 256; Nn = 64;  t = (b - 20) * 256 + threadIdx.x; }
  else if (b < 44) { w = uw1; out = u1f; K = 128; Nn = 256; t = (b - 28) * 256 + threadIdx.x; }
  else             { w = uw2; out = u2f; K = 256; Nn = 64;  t = (b - 44) * 256 + threadIdx.x; }
  int total = (K >> 5) * (Nn >> 4) * 64;
  if (t >= total) return;
  const bool permK = (K == 256);       // w2/u2: K side carries the hidden perm
  int lane = t & 63;
  int rest = t >> 6;
  int ntN = Nn >> 4;
  int nt = rest % ntN;
  int kt = rest / ntN;
  int n  = nt * 16 + (lane & 15);
  int k0 = kt * 32 + (lane >> 4) * 8;
  short* o = out + (size_t)t * 8;
#pragma unroll
  for (int j = 0; j < 8; ++j) {
    int kk = k0 + j;
    int kr = permK ? ((kk >> 6) * 4 + (kk & 3)) * 16 + ((kk >> 2) & 15) : kk;
    o[j] = f2bf(w[(size_t)kr * Nn + n]);
  }
}

// ---------------------------------------------------------------------------
// Counting sort of edges by dst: hist -> 2-level exclusive scan -> scatter.
// scan3 folded into scatter; agg zero folded into hist_k; s1/s2/cnt zero
// folded into scan2.
// ---------------------------------------------------------------------------
__global__ __launch_bounds__(256)
void hist_k(const int* __restrict__ ei, int* __restrict__ hist,
            float* __restrict__ agg) {
  int e = blockIdx.x * 256 + threadIdx.x;
  if (e >= N_EDGES) return;
  *(float4v*)(agg + (size_t)e * 4) = (float4v){0.f, 0.f, 0.f, 0.f};  // 3.2M floats
  atomicAdd(&hist[ei[N_EDGES + e]], 1);
}

__global__ __launch_bounds__(256)
void scan1(const int* __restrict__ hist, int* __restrict__ offs,
           int* __restrict__ bsums) {
  __shared__ int tmp[256];
  int i = blockIdx.x * 256 + threadIdx.x;
  int v = hist[i];
  tmp[threadIdx.x] = v;
  __syncthreads();
#pragma unroll
  for (int d = 1; d < 256; d <<= 1) {
    int t = (threadIdx.x >= d) ? tmp[threadIdx.x - d] : 0;
    __syncthreads();
    tmp[threadIdx.x] += t;
    __syncthreads();
  }
  offs[i] = tmp[threadIdx.x] - v;                 // exclusive within block
  if (threadIdx.x == 255) bsums[blockIdx.x] = tmp[255];
}

__global__ __launch_bounds__(256)
void scan2(const int* __restrict__ bsums, int* __restrict__ bpre,
           float* __restrict__ zstats) {
  // zero s1|s2|cnt (contiguous 8256 floats) — consumed by node_mlp later
  for (int i = threadIdx.x; i < 8256; i += 256) zstats[i] = 0.f;
  __shared__ int tmp[256];
  int v = (threadIdx.x < NB_SCAN) ? bsums[threadIdx.x] : 0;
  tmp[threadIdx.x] = v;
  __syncthreads();
#pragma unroll
  for (int d = 1; d < 256; d <<= 1) {
    int t = (threadIdx.x >= d) ? tmp[threadIdx.x - d] : 0;
    __syncthreads();
    tmp[threadIdx.x] += t;
    __syncthreads();
  }
  bpre[threadIdx.x] = tmp[threadIdx.x] - v;       // exclusive block prefix
}

__global__ __launch_bounds__(256)
void scatter_k(const int* __restrict__ ei, int* __restrict__ offs,
               const int* __restrict__ bpre, int* __restrict__ sorted) {
  int e = blockIdx.x * 256 + threadIdx.x;
  if (e >= N_EDGES) return;
  int d = ei[N_EDGES + e];
  int pos = atomicAdd(&offs[d], 1) + bpre[d >> 8];
  sorted[pos] = e;
}

// ---------------------------------------------------------------------------
// Edge MLP — block-cooperative, 64 dst-sorted edges / block.
// R15: sA and sH are SEPARATE buffers (sC aliases dead sA instead). The old
// b2 barrier existed only for the sA/sH alias; removing it lets each wave
// flow GEMM1 -> silu epilogue unsynced, overlapping one wave's VALU-heavy
// silu with another's MFMA. 3 barriers (was 4). LDS 56,064 B -> 2 blocks/CU.
// Reduce: per-wave 16-row run-reduce (R13; block-level version regressed in
// R14 via serial tail). + setprio + bf2[0] hoist (R13/R14 wins kept).
// ---------------------------------------------------------------------------
#define LDA_E 168   // 160 + 8 pad shorts; row = 336 B (16B aligned)
#define LDH   264   // 256 + 8 pad shorts; row = 528 B (16B aligned)
#define LDC   68    // fp32 stride of C tile (aliases sAbuf: 17408 <= 21504 B)

__global__ __launch_bounds__(256, 2)
void edge_mlp(const short* __restrict__ h_bf, const float* __restrict__ ea,
              const int* __restrict__ ei, const int* __restrict__ sorted,
              const short* __restrict__ w1f, const float* __restrict__ b1,
              const short* __restrict__ w2f, const float* __restrict__ b2,
              float* __restrict__ agg) {
  __shared__ __align__(16) short sAbuf[64 * LDA_E];  // 21504 B; sC alias later
  __shared__ __align__(16) short sHbuf[64 * LDH];    // 33792 B
  __shared__ int s_ids[4][48];                       // src[16], dst[16], eid[16]

  const int tid  = threadIdx.x;
  const int lane = tid & 63;
  const int wave = tid >> 6;
  const int col  = lane & 15;
  const int quad = lane >> 4;
  const int eb   = blockIdx.x * 64 + wave * 16;    // this wave's 16 sorted slots
  short* sA = sAbuf;
  short* sH = sHbuf;

  // ---- resolve sorted edge ids -> src/dst/eid (wave-local)
  if (lane < 48) {
    int i15 = lane & 15;
    int e0 = sorted[eb + i15];
    int v;
    if (lane < 16)      v = ei[e0];
    else if (lane < 32) v = ei[N_EDGES + e0];
    else                v = e0;
    s_ids[wave][lane] = v;
  }

  // ---- stage h_dst | h_src rows (bf16 copy, no conversion)
#pragma unroll
  for (int it = 0; it < 2; ++it) {
    int idx = it * 64 + lane;        // 0..127
    int e = idx >> 3, c = idx & 7;
    int row = wave * 16 + e;
    int d = s_ids[wave][16 + e];
    int s = s_ids[wave][e];
    *(short8*)&sA[row * LDA_E + c * 8] =
        *(const short8*)(h_bf + (size_t)d * D_MODEL + c * 8);
    *(short8*)&sA[row * LDA_E + 64 + c * 8] =
        *(const short8*)(h_bf + (size_t)s * D_MODEL + c * 8);
  }
  // ---- stage edge_attr (fp32 -> packed bf16)
#pragma unroll
  for (int it = 0; it < 2; ++it) {
    int idx = it * 64 + lane;        // 0..127
    int e = idx >> 3, j = idx & 7;
    int row = wave * 16 + e;
    int eid = s_ids[wave][32 + e];
    float4v v = *(const float4v*)(ea + (size_t)eid * 32 + j * 4);
    uint2v p = {pack_bf16x2(v.x, v.y), pack_bf16x2(v.z, v.w)};
    *(uint2v*)&sA[row * LDA_E + 128 + j * 4] = p;
  }
  __syncthreads();                                  // b1: sA visible

  // ---- GEMM1: [64,160] x [160,256]; wave covers n-tiles [4w, 4w+4)
  f32x4 acc[4][4];
#pragma unroll
  for (int mt = 0; mt < 4; ++mt)
#pragma unroll
    for (int nt = 0; nt < 4; ++nt)
      acc[mt][nt] = (f32x4){0.f, 0.f, 0.f, 0.f};

  short8 bf[2][4];
#pragma unroll
  for (int nt = 0; nt < 4; ++nt)
    bf[0][nt] = *(const short8*)(w1f + (size_t)((wave * 4 + nt) * 64 + lane) * 8);

#pragma unroll
  for (int kt = 0; kt < 5; ++kt) {
    if (kt < 4) {
#pragma unroll
      for (int nt = 0; nt < 4; ++nt)
        bf[(kt + 1) & 1][nt] = *(const short8*)(
            w1f + (size_t)(((kt + 1) * 16 + wave * 4 + nt) * 64 + lane) * 8);
    }
    short8 af[4];
#pragma unroll
    for (int mt = 0; mt < 4; ++mt)
      af[mt] = *(const short8*)&sA[(mt * 16 + col) * LDA_E + kt * 32 + quad * 8];
    __builtin_amdgcn_s_setprio(1);
#pragma unroll
    for (int nt = 0; nt < 4; ++nt)
#pragma unroll
      for (int mt = 0; mt < 4; ++mt)
        acc[mt][nt] = mfma16(af[mt], bf[kt & 1][nt], acc[mt][nt]);
    __builtin_amdgcn_s_setprio(0);
  }

  // ---- hoist GEMM2's first weight fragment (L2 latency hides under silu)
  short8 bf2[2];
  bf2[0] = *(const short8*)(w2f + (size_t)(wave * 64 + lane) * 8);

  // ---- bias + silu -> sH IMMEDIATELY (no barrier: sH separate from sA);
  // a fast wave's silu overlaps a slow wave's GEMM1 MFMA.
  {
    float b1v[4];
#pragma unroll
    for (int nt = 0; nt < 4; ++nt) b1v[nt] = b1[(wave * 4 + nt) * 16 + col];
#pragma unroll
    for (int mt = 0; mt < 4; ++mt) {
#pragma unroll
      for (int r = 0; r < 4; ++r) {
        const int row = mt * 16 + quad * 4 + r;
        float v0 = silu_f(acc[mt][0][r] + b1v[0]);
        float v1 = silu_f(acc[mt][1][r] + b1v[1]);
        float v2 = silu_f(acc[mt][2][r] + b1v[2]);
        float v3 = silu_f(acc[mt][3][r] + b1v[3]);
        uint2v p = {cvt_pk_bf16(v0, v1), cvt_pk_bf16(v2, v3)};
        *(uint2v*)&sH[row * LDH + wave * 64 + col * 4] = p;
      }
    }
  }
  __syncthreads();                                  // b3: sH visible (all sA reads done)

  // ---- GEMM2: [64,256] x [256,64]; wave covers n-tile `wave` (16 cols)
  f32x4 acc2[4];
#pragma unroll
  for (int mt = 0; mt < 4; ++mt) acc2[mt] = (f32x4){0.f, 0.f, 0.f, 0.f};

#pragma unroll
  for (int kt = 0; kt < 8; ++kt) {
    if (kt < 7)
      bf2[(kt + 1) & 1] = *(const short8*)(
          w2f + (size_t)(((kt + 1) * 4 + wave) * 64 + lane) * 8);
    short8 af[4];
#pragma unroll
    for (int mt = 0; mt < 4; ++mt)
      af[mt] = *(const short8*)&sH[(mt * 16 + col) * LDH + kt * 32 + quad * 8];
    __builtin_amdgcn_s_setprio(1);
#pragma unroll
    for (int mt = 0; mt < 4; ++mt)
      acc2[mt] = mfma16(af[mt], bf2[kt & 1], acc2[mt]);
    __builtin_amdgcn_s_setprio(0);
  }

  // ---- dump C (+bias) into sC (aliases sAbuf; all waves passed b3, so all
  // sA reads are long retired)
  {
    float* sC = (float*)sAbuf;
    const int n = wave * 16 + col;
    const float bias = b2[n];
#pragma unroll
    for (int mt = 0; mt < 4; ++mt)
#pragma unroll
      for (int r = 0; r < 4; ++r)
        sC[(mt * 16 + quad * 4 + r) * LDC + n] = acc2[mt][r] + bias;
  }
  __syncthreads();                                  // b4: sC visible

  // ---- run-reduce own 16 contiguous rows (dst-sorted): one atomic per run
  {
    const float* sC = (const float*)sAbuf;
    float sum = 0.f;
    int prev = s_ids[wave][16];
#pragma unroll
    for (int r = 0; r < 16; ++r) {
      float v = sC[(wave * 16 + r) * LDC + lane];
      int d = s_ids[wave][16 + r];          // LDS broadcast -> wave-uniform
      if (d != prev) {
        atomicAdd(agg + (size_t)prev * D_MODEL + lane, sum);
        sum = 0.f; prev = d;
      }
      sum += v;
    }
    atomicAdd(agg + (size_t)prev * D_MODEL + lane, sum);
  }
}

// ---------------------------------------------------------------------------
// Node MLP — block-cooperative, 64 nodes / block, fused GraphNorm stats.
// R15: separate sA/sH (b2 removed, 2 barriers); keeps R14 uniform-graph fast
// path (one s1/s2 atomic per feature per block for ~92% of blocks) + setprio
// + bf2[0] hoist.
// ---------------------------------------------------------------------------
#define LDA_N 136   // 128 + 8 pad shorts; row = 272 B (16B aligned)

__global__ __launch_bounds__(256, 2)
void node_mlp(const float* __restrict__ h, const short* __restrict__ h_bf,
              const float* __restrict__ agg,
              const short* __restrict__ w1f, const float* __restrict__ b1,
              const short* __restrict__ w2f, const float* __restrict__ b2,
              const int* __restrict__ batch,
              float* __restrict__ hnew,
              float* __restrict__ s1, float* __restrict__ s2,
              float* __restrict__ cnt) {
  __shared__ __align__(16) short sAbuf[64 * LDA_N];  // 17408 B
  __shared__ __align__(16) short sHbuf[64 * LDH];    // 33792 B
  __shared__ int s_b[64];                            // batch ids of block rows

  const int tid  = threadIdx.x;
  const int lane = tid & 63;
  const int wave = tid >> 6;
  const int col  = lane & 15;
  const int quad = lane >> 4;
  const int nb   = blockIdx.x * 64;
  short* sA = sAbuf;
  short* sH = sHbuf;

  if (tid < 64) {
    int gi = nb + tid;
    s_b[tid] = batch[(gi < N_NODES) ? gi : (N_NODES - 1)];
  }

  // ---- stage h rows (bf16 copy)
#pragma unroll
  for (int it = 0; it < 2; ++it) {
    int idx = it * 64 + lane;     // 0..127
    int i = idx >> 3, c = idx & 7;
    int row = wave * 16 + i;
    int gi = nb + row;
    if (gi >= N_NODES) gi = N_NODES - 1;
    *(short8*)&sA[row * LDA_N + c * 8] =
        *(const short8*)(h_bf + (size_t)gi * D_MODEL + c * 8);
  }
  // ---- stage agg rows (fp32 -> packed bf16)
#pragma unroll
  for (int it = 0; it < 4; ++it) {
    int idx = it * 64 + lane;     // 0..255
    int i = idx >> 4, j = idx & 15;
    int row = wave * 16 + i;
    int gi = nb + row;
    if (gi >= N_NODES) gi = N_NODES - 1;
    float4v v = *(const float4v*)(agg + (size_t)gi * D_MODEL + j * 4);
    uint2v p = {pack_bf16x2(v.x, v.y), pack_bf16x2(v.z, v.w)};
    *(uint2v*)&sA[row * LDA_N + 64 + j * 4] = p;
  }
  __syncthreads();                                  // b1: sA + s_b visible

  // ---- per-graph node counts (one wave; ballot run-length over 64 rows)
  if (wave == 3) {
    int gi = nb + lane;
    bool valid = gi < N_NODES;
    int g = s_b[lane];
    int gp = __shfl_up(g, 1);
    bool start = valid && (lane == 0 || g != gp);
    unsigned long long bmask = __ballot(start);
    unsigned long long imask = __ballot(!valid);
    if (start) {
      unsigned long long higher =
          (lane == 63) ? 0ULL : (((bmask | imask) >> (lane + 1)) << (lane + 1));
      int next = higher ? (__ffsll((long long)higher) - 1) : 64;
      atomicAdd(&cnt[g], (float)(next - lane));
    }
  }

  // ---- GEMM1: K=128; wave covers n-tiles [4w, 4w+4)
  f32x4 acc[4][4];
#pragma unroll
  for (int mt = 0; mt < 4; ++mt)
#pragma unroll
    for (int nt = 0; nt < 4; ++nt)
      acc[mt][nt] = (f32x4){0.f, 0.f, 0.f, 0.f};

  short8 bf[2][4];
#pragma unroll
  for (int nt = 0; nt < 4; ++nt)
    bf[0][nt] = *(const short8*)(w1f + (size_t)((wave * 4 + nt) * 64 + lane) * 8);

#pragma unroll
  for (int kt = 0; kt < 4; ++kt) {
    if (kt < 3) {
#pragma unroll
      for (int nt = 0; nt < 4; ++nt)
        bf[(kt + 1) & 1][nt] = *(const short8*)(
            w1f + (size_t)(((kt + 1) * 16 + wave * 4 + nt) * 64 + lane) * 8);
    }
    short8 af[4];
#pragma unroll
    for (int mt = 0; mt < 4; ++mt)
      af[mt] = *(const short8*)&sA[(mt * 16 + col) * LDA_N + kt * 32 + quad * 8];
    __builtin_amdgcn_s_setprio(1);
#pragma unroll
    for (int nt = 0; nt < 4; ++nt)
#pragma unroll
      for (int mt = 0; mt < 4; ++mt)
        acc[mt][nt] = mfma16(af[mt], bf[kt & 1][nt], acc[mt][nt]);
    __builtin_amdgcn_s_setprio(0);
  }

  // ---- hoist GEMM2's first weight fragment
  short8 bf2[2];
  bf2[0] = *(const short8*)(w2f + (size_t)(wave * 64 + lane) * 8);

  // ---- bias + silu -> sH immediately (separate buffer, no barrier)
  {
    float b1v[4];
#pragma unroll
    for (int nt = 0; nt < 4; ++nt) b1v[nt] = b1[(wave * 4 + nt) * 16 + col];
#pragma unroll
    for (int mt = 0; mt < 4; ++mt) {
#pragma unroll
      for (int r = 0; r < 4; ++r) {
        const int row = mt * 16 + quad * 4 + r;
        float v0 = silu_f(acc[mt][0][r] + b1v[0]);
        float v1 = silu_f(acc[mt][1][r] + b1v[1]);
        float v2 = silu_f(acc[mt][2][r] + b1v[2]);
        float v3 = silu_f(acc[mt][3][r] + b1v[3]);
        uint2v p = {cvt_pk_bf16(v0, v1), cvt_pk_bf16(v2, v3)};
        *(uint2v*)&sH[row * LDH + wave * 64 + col * 4] = p;
      }
    }
  }
  __syncthreads();                                  // b3: sH visible

  // ---- GEMM2: K=256; wave covers n-tile `wave`
  f32x4 acc2[4];
#pragma unroll
  for (int mt = 0; mt < 4; ++mt) acc2[mt] = (f32x4){0.f, 0.f, 0.f, 0.f};

#pragma unroll
  for (int kt = 0; kt < 8; ++kt) {
    if (kt < 7)
      bf2[(kt + 1) & 1] = *(const short8*)(
          w2f + (size_t)(((kt + 1) * 4 + wave) * 64 + lane) * 8);
    short8 af[4];
#pragma unroll
    for (int mt = 0; mt < 4; ++mt)
      af[mt] = *(const short8*)&sH[(mt * 16 + col) * LDH + kt * 32 + quad * 8];
    __builtin_amdgcn_s_setprio(1);
#pragma unroll
    for (int mt = 0; mt < 4; ++mt)
      acc2[mt] = mfma16(af[mt], bf2[kt & 1], acc2[mt]);
    __builtin_amdgcn_s_setprio(0);
  }

  // ---- epilogue: h_new = h + dh -> global + GraphNorm stat accumulation.
  {
    const int n = wave * 16 + col;
    const float bias = b2[n];
    const bool uni = (nb + 64 <= N_NODES) && (s_b[0] == s_b[63]);
    if (uni) {
      // fast path (~92% of blocks): whole block one graph, all rows valid
      const int g = s_b[0];
      float a1 = 0.f, a2 = 0.f;
#pragma unroll
      for (int mt = 0; mt < 4; ++mt) {
#pragma unroll
        for (int r = 0; r < 4; ++r) {
          const int gi = nb + mt * 16 + quad * 4 + r;
          float hv = h[(size_t)gi * D_MODEL + n] + acc2[mt][r] + bias;
          hnew[(size_t)gi * D_MODEL + n] = hv;
          a1 += hv; a2 += hv * hv;
        }
      }
      a1 += __shfl_xor(a1, 16); a1 += __shfl_xor(a1, 32);
      a2 += __shfl_xor(a2, 16); a2 += __shfl_xor(a2, 32);
      if (quad == 0) {
        atomicAdd(&s1[g * D_MODEL + n], a1);
        atomicAdd(&s2[g * D_MODEL + n], a2);
      }
    } else {
      float a1 = 0.f, a2 = 0.f;
      int prev = s_b[quad * 4];     // lane's first row (mt=0, r=0)
#pragma unroll
      for (int mt = 0; mt < 4; ++mt) {
#pragma unroll
        for (int r = 0; r < 4; ++r) {
          const int row = mt * 16 + quad * 4 + r;
          const int gi = nb + row;
          const bool valid = gi < N_NODES;
          int g = s_b[row];
          if (g != prev) {
            atomicAdd(&s1[prev * D_MODEL + n], a1);
            atomicAdd(&s2[prev * D_MODEL + n], a2);
            a1 = 0.f; a2 = 0.f; prev = g;
          }
          if (valid) {
            float hv = h[(size_t)gi * D_MODEL + n] + acc2[mt][r] + bias;
            hnew[(size_t)gi * D_MODEL + n] = hv;
            a1 += hv; a2 += hv * hv;
          }
        }
      }
      atomicAdd(&s1[prev * D_MODEL + n], a1);
      atomicAdd(&s2[prev * D_MODEL + n], a2);
    }
  }
}

// ---------------------------------------------------------------------------
// GraphNorm normalize (stats already produced by node_mlp).
// ---------------------------------------------------------------------------
__global__ __launch_bounds__(256)
void gn_norm(float* __restrict__ x, const int* __restrict__ batch,
             const float* __restrict__ s1, const float* __restrict__ s2,
             const float* __restrict__ cnt, const float* __restrict__ alpha,
             const float* __restrict__ weight, const float* __restrict__ bias) {
  int idx = blockIdx.x * 256 + threadIdx.x;
  if (idx >= N_NODES * D_MODEL) return;
  int i = idx >> 6, f = idx & 63;
  int g = batch[i];
  float c = fmaxf(cnt[g], 1.f);
  float m   = s1[g * D_MODEL + f] / c;
  float ex2 = s2[g * D_MODEL + f] / c;
  float a = alpha[f];
  float var = ex2 - 2.f * a * m * m + a * a * m * m;
  float hc = x[idx] - a * m;
  x[idx] = weight[f] * hc * rsqrtf(var + EPS_GN) + bias[f];
}

// ---------------------------------------------------------------------------
extern "C" void kernel_launch(void* const* d_in, const int* in_sizes, int n_in,
                              void* d_out, int out_size, void* d_ws, size_t ws_size,
                              hipStream_t stream) {
  const float* h     = (const float*)d_in[0];
  const float* ea    = (const float*)d_in[1];
  const int*   ei    = (const int*)d_in[2];   // [2][E], row0=src, row1=dst
  const int*   batch = (const int*)d_in[3];
  const float* mw1   = (const float*)d_in[4];
  const float* mb1   = (const float*)d_in[5];
  const float* mw2   = (const float*)d_in[6];
  const float* mb2   = (const float*)d_in[7];
  const float* uw1   = (const float*)d_in[8];
  const float* ub1   = (const float*)d_in[9];
  const float* uw2   = (const float*)d_in[10];
  const float* ub2   = (const float*)d_in[11];
  const float* gw    = (const float*)d_in[12];
  const float* gb    = (const float*)d_in[13];
  const float* ga    = (const float*)d_in[14];

  char* ws = (char*)d_ws;
  float* agg    = (float*)(ws + 0);             // 12,800,000 B
  short* w1f    = (short*)(ws + 12800000);      //     81,920 B
  short* w2f    = (short*)(ws + 12881920);      //     32,768 B
  short* u1f    = (short*)(ws + 12914688);      //     65,536 B
  short* u2f    = (short*)(ws + 12980224);      //     32,768 B
  float* s1     = (float*)(ws + 13012992);      //     16,384 B
  float* s2     = (float*)(ws + 13029376);      //     16,384 B
  float* cnt    = (float*)(ws + 13045760);      //        256 B
  int*   hist   = (int*)  (ws + 13046016);      //    200,704 B (50176 ints)
  int*   offs   = (int*)  (ws + 13246720);      //    200,704 B
  int*   bsums  = (int*)  (ws + 13447424);      //      1,024 B
  int*   bpre   = (int*)  (ws + 13448448);      //      1,024 B
  int*   sorted = (int*)  (ws + 13449472);      //  3,200,000 B
  short* h_bf   = (short*)(ws + 16649472);      //  6,400,000 B -> end 23,049,472

  float* zstats = (float*)(ws + 13012992);      // s1|s2|cnt contiguous (8256 f)

  // weights (52) + hist-zero (196) + h_bf (1563)
  prep_all<<<52 + 196 + HBF_BLOCKS, 256, 0, stream>>>(mw1, mw2, uw1, uw2, h,
                                                      w1f, w2f, u1f, u2f,
                                                      h_bf, hist);

  // counting sort of edges by dst (hist_k also zeroes agg)
  hist_k  <<<(N_EDGES + 255) / 256, 256, 0, stream>>>(ei, hist, agg);
  scan1   <<<NB_SCAN, 256, 0, stream>>>(hist, offs, bsums);
  scan2   <<<1, 256, 0, stream>>>(bsums, bpre, zstats);
  scatter_k<<<(N_EDGES + 255) / 256, 256, 0, stream>>>(ei, offs, bpre, sorted);

  edge_mlp<<<N_EDGES / 64, 256, 0, stream>>>(h_bf, ea, ei, sorted,
                                             w1f, mb1, w2f, mb2, agg);

  node_mlp<<<(N_NODES + 63) / 64, 256, 0, stream>>>(h, h_bf, agg,
                                                    u1f, ub1, u2f, ub2,
                                                    batch, (float*)d_out,
                                                    s1, s2, cnt);

  gn_norm<<<(N_NODES * D_MODEL + 255) / 256, 256, 0, stream>>>(
      (float*)d_out, batch, s1, s2, cnt, ga, gw, gb);
}

// Round 10
// 423.570 us; speedup vs baseline: 1.1108x; 1.1041x over previous
//
#include <hip/hip_runtime.h>
#include <hip/hip_bf16.h>
#include <stdint.h>

#define N_NODES   50000
#define N_EDGES   800000
#define D_MODEL   64
#define D_HIDDEN  256
#define N_GRAPHS  64
#define EPS_GN    1e-5f

#define NBINS_PAD 50176            // 196 * 256, zero-padded histogram
#define NB_SCAN   196

typedef __attribute__((ext_vector_type(8))) short short8;   // 8 bf16 (4 VGPRs)
typedef __attribute__((ext_vector_type(4))) float f32x4;
typedef __attribute__((ext_vector_type(4))) float float4v;
typedef __attribute__((ext_vector_type(2))) unsigned int uint2v;
typedef __attribute__((ext_vector_type(4))) unsigned int uint4v;

static __device__ __forceinline__ short f2bf(float f) {
  union { float f; uint32_t u; } v; v.f = f;
  uint32_t r = (v.u + 0x7fffu + ((v.u >> 16) & 1u)) >> 16;   // RNE
  return (short)(uint16_t)r;
}

// pack two fp32 -> bf16x2 (RNE), hi16 extraction fused via v_perm_b32
static __device__ __forceinline__ uint32_t pack_bf16x2(float lo, float hi) {
  union { float f; uint32_t u; } a, b;
  a.f = lo; b.f = hi;
  uint32_t ra = a.u + 0x7fffu + ((a.u >> 16) & 1u);
  uint32_t rb = b.u + 0x7fffu + ((b.u >> 16) & 1u);
  return __builtin_amdgcn_perm(rb, ra, 0x07060302u);  // {rb.b3,rb.b2,ra.b3,ra.b2}
}

// hw packed cvt: dst[15:0]=bf16(lo), dst[31:16]=bf16(hi)  (RNE in default mode)
static __device__ __forceinline__ uint32_t cvt_pk_bf16(float lo, float hi) {
  uint32_t r;
  asm("v_cvt_pk_bf16_f32 %0, %1, %2" : "=v"(r) : "v"(lo), "v"(hi));
  return r;
}

// fast silu: hardware rcp (rel err ~2^-22 << bf16 rounding) instead of IEEE div
static __device__ __forceinline__ float silu_f(float x) {
  return x * __builtin_amdgcn_rcpf(1.0f + __expf(-x));
}

static __device__ __forceinline__ f32x4 mfma16(short8 a, short8 b, f32x4 c) {
  return __builtin_amdgcn_mfma_f32_16x16x32_bf16(a, b, c, 0, 0, 0);
}

// ---------------------------------------------------------------------------
// Weight prep (4 mats -> MFMA B-frag layout) + hist zero + h -> bf16 copy.
// B-frag: [kt][nt][lane][8]; elem j of lane L = w[kt*32+(L>>4)*8+j][nt*16+(L&15)]
// For the K=256 matrices (w2/u2) the K dimension is PERMUTED: storage index kk
// holds logical hidden unit ((kk>>6)*4+(kk&3))*16+((kk>>2)&15), matching the
// packed epilogue-1 sH layout (ns = wave*64 + col*4 + nt).
// ---------------------------------------------------------------------------
#define HBF_BLOCKS 1563   // ceil(50000*64/8/256)

__global__ void prep_all(const float* __restrict__ mw1, const float* __restrict__ mw2,
                         const float* __restrict__ uw1, const float* __restrict__ uw2,
                         const float* __restrict__ h,
                         short* __restrict__ w1f, short* __restrict__ w2f,
                         short* __restrict__ u1f, short* __restrict__ u2f,
                         short* __restrict__ h_bf, int* __restrict__ hist) {
  int b = blockIdx.x;
  if (b >= 52 && b < 248) {            // zero histogram (196*256 = 50176 ints)
    hist[(b - 52) * 256 + threadIdx.x] = 0;
    return;
  }
  if (b >= 248) {                      // h -> bf16, 8 elems/thread
    int t2 = (b - 248) * 256 + threadIdx.x;
    if (t2 < N_NODES * D_MODEL / 8) {
      const float4v* src = (const float4v*)(h + (size_t)t2 * 8);
      float4v v0 = src[0], v1 = src[1];
      uint4v p = {pack_bf16x2(v0.x, v0.y), pack_bf16x2(v0.z, v0.w),
                  pack_bf16x2(v1.x, v1.y), pack_bf16x2(v1.z, v1.w)};
      *(uint4v*)(h_bf + (size_t)t2 * 8) = p;
    }
    return;
  }
  const float* w; short* out; int K, Nn, t;
  if (b < 20)      { w = mw1; out = w1f; K = 160; Nn = 256; t = b * 256 + threadIdx.x; }
  else if (b < 28) { w = mw2; out = w2f; K = 256; Nn = 64;  t = (b - 20) * 256 + threadIdx.x; }
  else if (b < 44) { w = uw1; out = u1f; K = 128; Nn = 256; t = (b - 28) * 256 + threadIdx.x; }
  else             { w = uw2; out = u2f; K = 256; Nn = 64;  t = (b - 44) * 256 + threadIdx.x; }
  int total = (K >> 5) * (Nn >> 4) * 64;
  if (t >= total) return;
  const bool permK = (K == 256);       // w2/u2: K side carries the hidden perm
  int lane = t & 63;
  int rest = t >> 6;
  int ntN = Nn >> 4;
  int nt = rest % ntN;
  int kt = rest / ntN;
  int n  = nt * 16 + (lane & 15);
  int k0 = kt * 32 + (lane >> 4) * 8;
  short* o = out + (size_t)t * 8;
#pragma unroll
  for (int j = 0; j < 8; ++j) {
    int kk = k0 + j;
    int kr = permK ? ((kk >> 6) * 4 + (kk & 3)) * 16 + ((kk >> 2) & 15) : kk;
    o[j] = f2bf(w[(size_t)kr * Nn + n]);
  }
}

// ---------------------------------------------------------------------------
// Counting sort of edges by dst: hist -> 2-level exclusive scan -> scatter.
// scan3 folded into scatter; agg zero folded into hist_k; s1/s2/cnt zero
// folded into scan2.
// ---------------------------------------------------------------------------
__global__ __launch_bounds__(256)
void hist_k(const int* __restrict__ ei, int* __restrict__ hist,
            float* __restrict__ agg) {
  int e = blockIdx.x * 256 + threadIdx.x;
  if (e >= N_EDGES) return;
  *(float4v*)(agg + (size_t)e * 4) = (float4v){0.f, 0.f, 0.f, 0.f};  // 3.2M floats
  atomicAdd(&hist[ei[N_EDGES + e]], 1);
}

__global__ __launch_bounds__(256)
void scan1(const int* __restrict__ hist, int* __restrict__ offs,
           int* __restrict__ bsums) {
  __shared__ int tmp[256];
  int i = blockIdx.x * 256 + threadIdx.x;
  int v = hist[i];
  tmp[threadIdx.x] = v;
  __syncthreads();
#pragma unroll
  for (int d = 1; d < 256; d <<= 1) {
    int t = (threadIdx.x >= d) ? tmp[threadIdx.x - d] : 0;
    __syncthreads();
    tmp[threadIdx.x] += t;
    __syncthreads();
  }
  offs[i] = tmp[threadIdx.x] - v;                 // exclusive within block
  if (threadIdx.x == 255) bsums[blockIdx.x] = tmp[255];
}

__global__ __launch_bounds__(256)
void scan2(const int* __restrict__ bsums, int* __restrict__ bpre,
           float* __restrict__ zstats) {
  // zero s1|s2|cnt (contiguous 8256 floats) — consumed by node_mlp later
  for (int i = threadIdx.x; i < 8256; i += 256) zstats[i] = 0.f;
  __shared__ int tmp[256];
  int v = (threadIdx.x < NB_SCAN) ? bsums[threadIdx.x] : 0;
  tmp[threadIdx.x] = v;
  __syncthreads();
#pragma unroll
  for (int d = 1; d < 256; d <<= 1) {
    int t = (threadIdx.x >= d) ? tmp[threadIdx.x - d] : 0;
    __syncthreads();
    tmp[threadIdx.x] += t;
    __syncthreads();
  }
  bpre[threadIdx.x] = tmp[threadIdx.x] - v;       // exclusive block prefix
}

__global__ __launch_bounds__(256)
void scatter_k(const int* __restrict__ ei, int* __restrict__ offs,
               const int* __restrict__ bpre, int* __restrict__ sorted) {
  int e = blockIdx.x * 256 + threadIdx.x;
  if (e >= N_EDGES) return;
  int d = ei[N_EDGES + e];
  int pos = atomicAdd(&offs[d], 1) + bpre[d >> 8];
  sorted[pos] = e;
}

// ---------------------------------------------------------------------------
// Edge MLP — block-cooperative, 64 dst-sorted edges / block.
// R16 = R13 exactly (measured 171.5 us: aliased sA/sH buf + separate sC,
// 4 barriers, per-wave run-reduce, setprio, (256,2) -> LDS 52,224 = 3 blk/CU;
// R9 lesson: de-aliasing crosses the 3->2 block cliff, barrier removal loses)
// + R14's harmless bf2[0] hoist.
// ---------------------------------------------------------------------------
#define LDA_E 168   // 160 + 8 pad shorts; row = 336 B (16B aligned)
#define LDH   264   // 256 + 8 pad shorts; row = 528 B (16B aligned)
#define LDC   68    // fp32 stride of C tile

__global__ __launch_bounds__(256, 2)
void edge_mlp(const short* __restrict__ h_bf, const float* __restrict__ ea,
              const int* __restrict__ ei, const int* __restrict__ sorted,
              const short* __restrict__ w1f, const float* __restrict__ b1,
              const short* __restrict__ w2f, const float* __restrict__ b2,
              float* __restrict__ agg) {
  __shared__ __align__(16) short buf[64 * LDH];    // sA [64][LDA_E] then sH
  __shared__ __align__(16) float sC[64 * LDC];     // 17408 B
  __shared__ int s_ids[4][48];                     // src[16], dst[16], eid[16]

  const int tid  = threadIdx.x;
  const int lane = tid & 63;
  const int wave = tid >> 6;
  const int col  = lane & 15;
  const int quad = lane >> 4;
  const int eb   = blockIdx.x * 64 + wave * 16;    // this wave's 16 sorted slots
  short* sA = buf;
  short* sH = buf;

  // ---- resolve sorted edge ids -> src/dst/eid (wave-local)
  if (lane < 48) {
    int i15 = lane & 15;
    int e0 = sorted[eb + i15];
    int v;
    if (lane < 16)      v = ei[e0];
    else if (lane < 32) v = ei[N_EDGES + e0];
    else                v = e0;
    s_ids[wave][lane] = v;
  }

  // ---- stage h_dst | h_src rows (bf16 copy, no conversion)
#pragma unroll
  for (int it = 0; it < 2; ++it) {
    int idx = it * 64 + lane;        // 0..127
    int e = idx >> 3, c = idx & 7;
    int row = wave * 16 + e;
    int d = s_ids[wave][16 + e];
    int s = s_ids[wave][e];
    *(short8*)&sA[row * LDA_E + c * 8] =
        *(const short8*)(h_bf + (size_t)d * D_MODEL + c * 8);
    *(short8*)&sA[row * LDA_E + 64 + c * 8] =
        *(const short8*)(h_bf + (size_t)s * D_MODEL + c * 8);
  }
  // ---- stage edge_attr (fp32 -> packed bf16)
#pragma unroll
  for (int it = 0; it < 2; ++it) {
    int idx = it * 64 + lane;        // 0..127
    int e = idx >> 3, j = idx & 7;
    int row = wave * 16 + e;
    int eid = s_ids[wave][32 + e];
    float4v v = *(const float4v*)(ea + (size_t)eid * 32 + j * 4);
    uint2v p = {pack_bf16x2(v.x, v.y), pack_bf16x2(v.z, v.w)};
    *(uint2v*)&sA[row * LDA_E + 128 + j * 4] = p;
  }
  __syncthreads();                                  // b1: sA visible

  // ---- GEMM1: [64,160] x [160,256]; wave covers n-tiles [4w, 4w+4)
  f32x4 acc[4][4];
#pragma unroll
  for (int mt = 0; mt < 4; ++mt)
#pragma unroll
    for (int nt = 0; nt < 4; ++nt)
      acc[mt][nt] = (f32x4){0.f, 0.f, 0.f, 0.f};

  short8 bf[2][4];
#pragma unroll
  for (int nt = 0; nt < 4; ++nt)
    bf[0][nt] = *(const short8*)(w1f + (size_t)((wave * 4 + nt) * 64 + lane) * 8);

#pragma unroll
  for (int kt = 0; kt < 5; ++kt) {
    if (kt < 4) {
#pragma unroll
      for (int nt = 0; nt < 4; ++nt)
        bf[(kt + 1) & 1][nt] = *(const short8*)(
            w1f + (size_t)(((kt + 1) * 16 + wave * 4 + nt) * 64 + lane) * 8);
    }
    short8 af[4];
#pragma unroll
    for (int mt = 0; mt < 4; ++mt)
      af[mt] = *(const short8*)&sA[(mt * 16 + col) * LDA_E + kt * 32 + quad * 8];
    __builtin_amdgcn_s_setprio(1);
#pragma unroll
    for (int nt = 0; nt < 4; ++nt)
#pragma unroll
      for (int mt = 0; mt < 4; ++mt)
        acc[mt][nt] = mfma16(af[mt], bf[kt & 1][nt], acc[mt][nt]);
    __builtin_amdgcn_s_setprio(0);
  }

  // ---- hoist GEMM2's first weight fragment (L2 latency hides under silu)
  short8 bf2[2];
  bf2[0] = *(const short8*)(w2f + (size_t)(wave * 64 + lane) * 8);

  __syncthreads();                                  // b2: sA dead, safe to reuse

  // ---- bias + silu -> sH, permuted-hidden packed writes:
  // storage col ns = wave*64 + col*4 + nt  (4 consecutive shorts per lane)
  {
    float b1v[4];
#pragma unroll
    for (int nt = 0; nt < 4; ++nt) b1v[nt] = b1[(wave * 4 + nt) * 16 + col];
#pragma unroll
    for (int mt = 0; mt < 4; ++mt) {
#pragma unroll
      for (int r = 0; r < 4; ++r) {
        const int row = mt * 16 + quad * 4 + r;
        float v0 = silu_f(acc[mt][0][r] + b1v[0]);
        float v1 = silu_f(acc[mt][1][r] + b1v[1]);
        float v2 = silu_f(acc[mt][2][r] + b1v[2]);
        float v3 = silu_f(acc[mt][3][r] + b1v[3]);
        uint2v p = {cvt_pk_bf16(v0, v1), cvt_pk_bf16(v2, v3)};
        *(uint2v*)&sH[row * LDH + wave * 64 + col * 4] = p;
      }
    }
  }
  __syncthreads();                                  // b3: sH visible

  // ---- GEMM2: [64,256] x [256,64]; wave covers n-tile `wave` (16 cols)
  f32x4 acc2[4];
#pragma unroll
  for (int mt = 0; mt < 4; ++mt) acc2[mt] = (f32x4){0.f, 0.f, 0.f, 0.f};

#pragma unroll
  for (int kt = 0; kt < 8; ++kt) {
    if (kt < 7)
      bf2[(kt + 1) & 1] = *(const short8*)(
          w2f + (size_t)(((kt + 1) * 4 + wave) * 64 + lane) * 8);
    short8 af[4];
#pragma unroll
    for (int mt = 0; mt < 4; ++mt)
      af[mt] = *(const short8*)&sH[(mt * 16 + col) * LDH + kt * 32 + quad * 8];
    __builtin_amdgcn_s_setprio(1);
#pragma unroll
    for (int mt = 0; mt < 4; ++mt)
      acc2[mt] = mfma16(af[mt], bf2[kt & 1], acc2[mt]);
    __builtin_amdgcn_s_setprio(0);
  }

  // ---- dump C (+bias) into separate sC tile (no barrier needed before)
  {
    const int n = wave * 16 + col;
    const float bias = b2[n];
#pragma unroll
    for (int mt = 0; mt < 4; ++mt)
#pragma unroll
      for (int r = 0; r < 4; ++r)
        sC[(mt * 16 + quad * 4 + r) * LDC + n] = acc2[mt][r] + bias;
  }
  __syncthreads();                                  // b4: sC visible

  // ---- run-reduce own 16 contiguous rows (dst-sorted): one atomic per run
  {
    float sum = 0.f;
    int prev = s_ids[wave][16];
#pragma unroll
    for (int r = 0; r < 16; ++r) {
      float v = sC[(wave * 16 + r) * LDC + lane];
      int d = s_ids[wave][16 + r];          // LDS broadcast -> wave-uniform
      if (d != prev) {
        atomicAdd(agg + (size_t)prev * D_MODEL + lane, sum);
        sum = 0.f; prev = d;
      }
      sum += v;
    }
    atomicAdd(agg + (size_t)prev * D_MODEL + lane, sum);
  }
}

// ---------------------------------------------------------------------------
// Node MLP — block-cooperative, 64 nodes / block, fused GraphNorm stats.
// R16 = R14 exactly (measured as part of rest=255.9 us): aliased buf,
// uniform-graph fast path (one s1/s2 atomic per feature for ~92% of blocks),
// setprio, bf2[0] hoist, (256,2).
// ---------------------------------------------------------------------------
#define LDA_N 136   // 128 + 8 pad shorts; row = 272 B (16B aligned)

__global__ __launch_bounds__(256, 2)
void node_mlp(const float* __restrict__ h, const short* __restrict__ h_bf,
              const float* __restrict__ agg,
              const short* __restrict__ w1f, const float* __restrict__ b1,
              const short* __restrict__ w2f, const float* __restrict__ b2,
              const int* __restrict__ batch,
              float* __restrict__ hnew,
              float* __restrict__ s1, float* __restrict__ s2,
              float* __restrict__ cnt) {
  __shared__ __align__(16) short buf[64 * LDH];    // sA [64][LDA_N] then sH
  __shared__ int s_b[64];                          // batch ids of block rows

  const int tid  = threadIdx.x;
  const int lane = tid & 63;
  const int wave = tid >> 6;
  const int col  = lane & 15;
  const int quad = lane >> 4;
  const int nb   = blockIdx.x * 64;
  short* sA = buf;
  short* sH = buf;

  if (tid < 64) {
    int gi = nb + tid;
    s_b[tid] = batch[(gi < N_NODES) ? gi : (N_NODES - 1)];
  }

  // ---- stage h rows (bf16 copy)
#pragma unroll
  for (int it = 0; it < 2; ++it) {
    int idx = it * 64 + lane;     // 0..127
    int i = idx >> 3, c = idx & 7;
    int row = wave * 16 + i;
    int gi = nb + row;
    if (gi >= N_NODES) gi = N_NODES - 1;
    *(short8*)&sA[row * LDA_N + c * 8] =
        *(const short8*)(h_bf + (size_t)gi * D_MODEL + c * 8);
  }
  // ---- stage agg rows (fp32 -> packed bf16)
#pragma unroll
  for (int it = 0; it < 4; ++it) {
    int idx = it * 64 + lane;     // 0..255
    int i = idx >> 4, j = idx & 15;
    int row = wave * 16 + i;
    int gi = nb + row;
    if (gi >= N_NODES) gi = N_NODES - 1;
    float4v v = *(const float4v*)(agg + (size_t)gi * D_MODEL + j * 4);
    uint2v p = {pack_bf16x2(v.x, v.y), pack_bf16x2(v.z, v.w)};
    *(uint2v*)&sA[row * LDA_N + 64 + j * 4] = p;
  }
  __syncthreads();                                  // b1

  // ---- per-graph node counts (one wave; ballot run-length over 64 rows)
  if (wave == 3) {
    int gi = nb + lane;
    bool valid = gi < N_NODES;
    int g = s_b[lane];
    int gp = __shfl_up(g, 1);
    bool start = valid && (lane == 0 || g != gp);
    unsigned long long bmask = __ballot(start);
    unsigned long long imask = __ballot(!valid);
    if (start) {
      unsigned long long higher =
          (lane == 63) ? 0ULL : (((bmask | imask) >> (lane + 1)) << (lane + 1));
      int next = higher ? (__ffsll((long long)higher) - 1) : 64;
      atomicAdd(&cnt[g], (float)(next - lane));
    }
  }

  // ---- GEMM1: K=128; wave covers n-tiles [4w, 4w+4)
  f32x4 acc[4][4];
#pragma unroll
  for (int mt = 0; mt < 4; ++mt)
#pragma unroll
    for (int nt = 0; nt < 4; ++nt)
      acc[mt][nt] = (f32x4){0.f, 0.f, 0.f, 0.f};

  short8 bf[2][4];
#pragma unroll
  for (int nt = 0; nt < 4; ++nt)
    bf[0][nt] = *(const short8*)(w1f + (size_t)((wave * 4 + nt) * 64 + lane) * 8);

#pragma unroll
  for (int kt = 0; kt < 4; ++kt) {
    if (kt < 3) {
#pragma unroll
      for (int nt = 0; nt < 4; ++nt)
        bf[(kt + 1) & 1][nt] = *(const short8*)(
            w1f + (size_t)(((kt + 1) * 16 + wave * 4 + nt) * 64 + lane) * 8);
    }
    short8 af[4];
#pragma unroll
    for (int mt = 0; mt < 4; ++mt)
      af[mt] = *(const short8*)&sA[(mt * 16 + col) * LDA_N + kt * 32 + quad * 8];
    __builtin_amdgcn_s_setprio(1);
#pragma unroll
    for (int nt = 0; nt < 4; ++nt)
#pragma unroll
      for (int mt = 0; mt < 4; ++mt)
        acc[mt][nt] = mfma16(af[mt], bf[kt & 1][nt], acc[mt][nt]);
    __builtin_amdgcn_s_setprio(0);
  }

  // ---- hoist GEMM2's first weight fragment
  short8 bf2[2];
  bf2[0] = *(const short8*)(w2f + (size_t)(wave * 64 + lane) * 8);

  __syncthreads();                                  // b2: sA dead

  // ---- bias + silu -> sH, permuted-hidden packed writes (matches u2f perm)
  {
    float b1v[4];
#pragma unroll
    for (int nt = 0; nt < 4; ++nt) b1v[nt] = b1[(wave * 4 + nt) * 16 + col];
#pragma unroll
    for (int mt = 0; mt < 4; ++mt) {
#pragma unroll
      for (int r = 0; r < 4; ++r) {
        const int row = mt * 16 + quad * 4 + r;
        float v0 = silu_f(acc[mt][0][r] + b1v[0]);
        float v1 = silu_f(acc[mt][1][r] + b1v[1]);
        float v2 = silu_f(acc[mt][2][r] + b1v[2]);
        float v3 = silu_f(acc[mt][3][r] + b1v[3]);
        uint2v p = {cvt_pk_bf16(v0, v1), cvt_pk_bf16(v2, v3)};
        *(uint2v*)&sH[row * LDH + wave * 64 + col * 4] = p;
      }
    }
  }
  __syncthreads();                                  // b3: sH visible

  // ---- GEMM2: K=256; wave covers n-tile `wave`
  f32x4 acc2[4];
#pragma unroll
  for (int mt = 0; mt < 4; ++mt) acc2[mt] = (f32x4){0.f, 0.f, 0.f, 0.f};

#pragma unroll
  for (int kt = 0; kt < 8; ++kt) {
    if (kt < 7)
      bf2[(kt + 1) & 1] = *(const short8*)(
          w2f + (size_t)(((kt + 1) * 4 + wave) * 64 + lane) * 8);
    short8 af[4];
#pragma unroll
    for (int mt = 0; mt < 4; ++mt)
      af[mt] = *(const short8*)&sH[(mt * 16 + col) * LDH + kt * 32 + quad * 8];
    __builtin_amdgcn_s_setprio(1);
#pragma unroll
    for (int mt = 0; mt < 4; ++mt)
      acc2[mt] = mfma16(af[mt], bf2[kt & 1], acc2[mt]);
    __builtin_amdgcn_s_setprio(0);
  }

  // ---- epilogue: h_new = h + dh -> global + GraphNorm stat accumulation.
  {
    const int n = wave * 16 + col;
    const float bias = b2[n];
    const bool uni = (nb + 64 <= N_NODES) && (s_b[0] == s_b[63]);
    if (uni) {
      // fast path (~92% of blocks): whole block one graph, all rows valid
      const int g = s_b[0];
      float a1 = 0.f, a2 = 0.f;
#pragma unroll
      for (int mt = 0; mt < 4; ++mt) {
#pragma unroll
        for (int r = 0; r < 4; ++r) {
          const int gi = nb + mt * 16 + quad * 4 + r;
          float hv = h[(size_t)gi * D_MODEL + n] + acc2[mt][r] + bias;
          hnew[(size_t)gi * D_MODEL + n] = hv;
          a1 += hv; a2 += hv * hv;
        }
      }
      a1 += __shfl_xor(a1, 16); a1 += __shfl_xor(a1, 32);
      a2 += __shfl_xor(a2, 16); a2 += __shfl_xor(a2, 32);
      if (quad == 0) {
        atomicAdd(&s1[g * D_MODEL + n], a1);
        atomicAdd(&s2[g * D_MODEL + n], a2);
      }
    } else {
      float a1 = 0.f, a2 = 0.f;
      int prev = s_b[quad * 4];     // lane's first row (mt=0, r=0)
#pragma unroll
      for (int mt = 0; mt < 4; ++mt) {
#pragma unroll
        for (int r = 0; r < 4; ++r) {
          const int row = mt * 16 + quad * 4 + r;
          const int gi = nb + row;
          const bool valid = gi < N_NODES;
          int g = s_b[row];
          if (g != prev) {
            atomicAdd(&s1[prev * D_MODEL + n], a1);
            atomicAdd(&s2[prev * D_MODEL + n], a2);
            a1 = 0.f; a2 = 0.f; prev = g;
          }
          if (valid) {
            float hv = h[(size_t)gi * D_MODEL + n] + acc2[mt][r] + bias;
            hnew[(size_t)gi * D_MODEL + n] = hv;
            a1 += hv; a2 += hv * hv;
          }
        }
      }
      atomicAdd(&s1[prev * D_MODEL + n], a1);
      atomicAdd(&s2[prev * D_MODEL + n], a2);
    }
  }
}

// ---------------------------------------------------------------------------
// GraphNorm normalize (stats already produced by node_mlp).
// ---------------------------------------------------------------------------
__global__ __launch_bounds__(256)
void gn_norm(float* __restrict__ x, const int* __restrict__ batch,
             const float* __restrict__ s1, const float* __restrict__ s2,
             const float* __restrict__ cnt, const float* __restrict__ alpha,
             const float* __restrict__ weight, const float* __restrict__ bias) {
  int idx = blockIdx.x * 256 + threadIdx.x;
  if (idx >= N_NODES * D_MODEL) return;
  int i = idx >> 6, f = idx & 63;
  int g = batch[i];
  float c = fmaxf(cnt[g], 1.f);
  float m   = s1[g * D_MODEL + f] / c;
  float ex2 = s2[g * D_MODEL + f] / c;
  float a = alpha[f];
  float var = ex2 - 2.f * a * m * m + a * a * m * m;
  float hc = x[idx] - a * m;
  x[idx] = weight[f] * hc * rsqrtf(var + EPS_GN) + bias[f];
}

// ---------------------------------------------------------------------------
extern "C" void kernel_launch(void* const* d_in, const int* in_sizes, int n_in,
                              void* d_out, int out_size, void* d_ws, size_t ws_size,
                              hipStream_t stream) {
  const float* h     = (const float*)d_in[0];
  const float* ea    = (const float*)d_in[1];
  const int*   ei    = (const int*)d_in[2];   // [2][E], row0=src, row1=dst
  const int*   batch = (const int*)d_in[3];
  const float* mw1   = (const float*)d_in[4];
  const float* mb1   = (const float*)d_in[5];
  const float* mw2   = (const float*)d_in[6];
  const float* mb2   = (const float*)d_in[7];
  const float* uw1   = (const float*)d_in[8];
  const float* ub1   = (const float*)d_in[9];
  const float* uw2   = (const float*)d_in[10];
  const float* ub2   = (const float*)d_in[11];
  const float* gw    = (const float*)d_in[12];
  const float* gb    = (const float*)d_in[13];
  const float* ga    = (const float*)d_in[14];

  char* ws = (char*)d_ws;
  float* agg    = (float*)(ws + 0);             // 12,800,000 B
  short* w1f    = (short*)(ws + 12800000);      //     81,920 B
  short* w2f    = (short*)(ws + 12881920);      //     32,768 B
  short* u1f    = (short*)(ws + 12914688);      //     65,536 B
  short* u2f    = (short*)(ws + 12980224);      //     32,768 B
  float* s1     = (float*)(ws + 13012992);      //     16,384 B
  float* s2     = (float*)(ws + 13029376);      //     16,384 B
  float* cnt    = (float*)(ws + 13045760);      //        256 B
  int*   hist   = (int*)  (ws + 13046016);      //    200,704 B (50176 ints)
  int*   offs   = (int*)  (ws + 13246720);      //    200,704 B
  int*   bsums  = (int*)  (ws + 13447424);      //      1,024 B
  int*   bpre   = (int*)  (ws + 13448448);      //      1,024 B
  int*   sorted = (int*)  (ws + 13449472);      //  3,200,000 B
  short* h_bf   = (short*)(ws + 16649472);      //  6,400,000 B -> end 23,049,472

  float* zstats = (float*)(ws + 13012992);      // s1|s2|cnt contiguous (8256 f)

  // weights (52) + hist-zero (196) + h_bf (1563)
  prep_all<<<52 + 196 + HBF_BLOCKS, 256, 0, stream>>>(mw1, mw2, uw1, uw2, h,
                                                      w1f, w2f, u1f, u2f,
                                                      h_bf, hist);

  // counting sort of edges by dst (hist_k also zeroes agg)
  hist_k  <<<(N_EDGES + 255) / 256, 256, 0, stream>>>(ei, hist, agg);
  scan1   <<<NB_SCAN, 256, 0, stream>>>(hist, offs, bsums);
  scan2   <<<1, 256, 0, stream>>>(bsums, bpre, zstats);
  scatter_k<<<(N_EDGES + 255) / 256, 256, 0, stream>>>(ei, offs, bpre, sorted);

  edge_mlp<<<N_EDGES / 64, 256, 0, stream>>>(h_bf, ea, ei, sorted,
                                             w1f, mb1, w2f, mb2, agg);

  node_mlp<<<(N_NODES + 63) / 64, 256, 0, stream>>>(h, h_bf, agg,
                                                    u1f, ub1, u2f, ub2,
                                                    batch, (float*)d_out,
                                                    s1, s2, cnt);

  gn_norm<<<(N_NODES * D_MODEL + 255) / 256, 256, 0, stream>>>(
      (float*)d_out, batch, s1, s2, cnt, ga, gw, gb);
}

// Round 11
// 422.030 us; speedup vs baseline: 1.1149x; 1.0036x over previous
//
#include <hip/hip_runtime.h>
#include <hip/hip_bf16.h>
#include <stdint.h>

#define N_NODES   50000
#define N_EDGES   800000
#define D_MODEL   64
#define D_HIDDEN  256
#define N_GRAPHS  64
#define EPS_GN    1e-5f

#define NBINS_PAD 50176            // 196 * 256, zero-padded histogram
#define NB_SCAN   196

typedef __attribute__((ext_vector_type(8))) short short8;   // 8 bf16 (4 VGPRs)
typedef __attribute__((ext_vector_type(4))) float f32x4;
typedef __attribute__((ext_vector_type(4))) float float4v;
typedef __attribute__((ext_vector_type(2))) unsigned int uint2v;
typedef __attribute__((ext_vector_type(4))) unsigned int uint4v;

static __device__ __forceinline__ short f2bf(float f) {
  union { float f; uint32_t u; } v; v.f = f;
  uint32_t r = (v.u + 0x7fffu + ((v.u >> 16) & 1u)) >> 16;   // RNE
  return (short)(uint16_t)r;
}

// pack two fp32 -> bf16x2 (RNE), hi16 extraction fused via v_perm_b32
static __device__ __forceinline__ uint32_t pack_bf16x2(float lo, float hi) {
  union { float f; uint32_t u; } a, b;
  a.f = lo; b.f = hi;
  uint32_t ra = a.u + 0x7fffu + ((a.u >> 16) & 1u);
  uint32_t rb = b.u + 0x7fffu + ((b.u >> 16) & 1u);
  return __builtin_amdgcn_perm(rb, ra, 0x07060302u);  // {rb.b3,rb.b2,ra.b3,ra.b2}
}

// hw packed cvt: dst[15:0]=bf16(lo), dst[31:16]=bf16(hi)  (RNE in default mode)
static __device__ __forceinline__ uint32_t cvt_pk_bf16(float lo, float hi) {
  uint32_t r;
  asm("v_cvt_pk_bf16_f32 %0, %1, %2" : "=v"(r) : "v"(lo), "v"(hi));
  return r;
}

// fast silu: hardware rcp (rel err ~2^-22 << bf16 rounding) instead of IEEE div
static __device__ __forceinline__ float silu_f(float x) {
  return x * __builtin_amdgcn_rcpf(1.0f + __expf(-x));
}

static __device__ __forceinline__ f32x4 mfma16(short8 a, short8 b, f32x4 c) {
  return __builtin_amdgcn_mfma_f32_16x16x32_bf16(a, b, c, 0, 0, 0);
}

// async global->LDS, 16B per lane; LDS dest = wave-uniform base + lane*16
static __device__ __forceinline__ void gload_lds16(const short* g, short* l) {
  __builtin_amdgcn_global_load_lds(
      (const __attribute__((address_space(1))) void*)g,
      (__attribute__((address_space(3))) void*)l, 16, 0, 0);
}

// ---------------------------------------------------------------------------
// Weight prep (4 mats -> MFMA B-frag layout) + hist zero + h -> bf16 copy.
// B-frag: [kt][nt][lane][8]; elem j of lane L = w[kt*32+(L>>4)*8+j][nt*16+(L&15)]
// For the K=256 matrices (w2/u2) the K dimension is PERMUTED: storage index kk
// holds logical hidden unit ((kk>>6)*4+(kk&3))*16+((kk>>2)&15), matching the
// packed epilogue-1 sH layout (ns = wave*64 + col*4 + nt).
// ---------------------------------------------------------------------------
#define HBF_BLOCKS 1563   // ceil(50000*64/8/256)

__global__ void prep_all(const float* __restrict__ mw1, const float* __restrict__ mw2,
                         const float* __restrict__ uw1, const float* __restrict__ uw2,
                         const float* __restrict__ h,
                         short* __restrict__ w1f, short* __restrict__ w2f,
                         short* __restrict__ u1f, short* __restrict__ u2f,
                         short* __restrict__ h_bf, int* __restrict__ hist) {
  int b = blockIdx.x;
  if (b >= 52 && b < 248) {            // zero histogram (196*256 = 50176 ints)
    hist[(b - 52) * 256 + threadIdx.x] = 0;
    return;
  }
  if (b >= 248) {                      // h -> bf16, 8 elems/thread
    int t2 = (b - 248) * 256 + threadIdx.x;
    if (t2 < N_NODES * D_MODEL / 8) {
      const float4v* src = (const float4v*)(h + (size_t)t2 * 8);
      float4v v0 = src[0], v1 = src[1];
      uint4v p = {pack_bf16x2(v0.x, v0.y), pack_bf16x2(v0.z, v0.w),
                  pack_bf16x2(v1.x, v1.y), pack_bf16x2(v1.z, v1.w)};
      *(uint4v*)(h_bf + (size_t)t2 * 8) = p;
    }
    return;
  }
  const float* w; short* out; int K, Nn, t;
  if (b < 20)      { w = mw1; out = w1f; K = 160; Nn = 256; t = b * 256 + threadIdx.x; }
  else if (b < 28) { w = mw2; out = w2f; K = 256; Nn = 64;  t = (b - 20) * 256 + threadIdx.x; }
  else if (b < 44) { w = uw1; out = u1f; K = 128; Nn = 256; t = (b - 28) * 256 + threadIdx.x; }
  else             { w = uw2; out = u2f; K = 256; Nn = 64;  t = (b - 44) * 256 + threadIdx.x; }
  int total = (K >> 5) * (Nn >> 4) * 64;
  if (t >= total) return;
  const bool permK = (K == 256);       // w2/u2: K side carries the hidden perm
  int lane = t & 63;
  int rest = t >> 6;
  int ntN = Nn >> 4;
  int nt = rest % ntN;
  int kt = rest / ntN;
  int n  = nt * 16 + (lane & 15);
  int k0 = kt * 32 + (lane >> 4) * 8;
  short* o = out + (size_t)t * 8;
#pragma unroll
  for (int j = 0; j < 8; ++j) {
    int kk = k0 + j;
    int kr = permK ? ((kk >> 6) * 4 + (kk & 3)) * 16 + ((kk >> 2) & 15) : kk;
    o[j] = f2bf(w[(size_t)kr * Nn + n]);
  }
}

// ---------------------------------------------------------------------------
// Counting sort of edges by dst: hist -> 2-level exclusive scan -> scatter.
// scan3 folded into scatter; agg zero folded into hist_k; s1/s2/cnt zero
// folded into scan2.
// ---------------------------------------------------------------------------
__global__ __launch_bounds__(256)
void hist_k(const int* __restrict__ ei, int* __restrict__ hist,
            float* __restrict__ agg) {
  int e = blockIdx.x * 256 + threadIdx.x;
  if (e >= N_EDGES) return;
  *(float4v*)(agg + (size_t)e * 4) = (float4v){0.f, 0.f, 0.f, 0.f};  // 3.2M floats
  atomicAdd(&hist[ei[N_EDGES + e]], 1);
}

__global__ __launch_bounds__(256)
void scan1(const int* __restrict__ hist, int* __restrict__ offs,
           int* __restrict__ bsums) {
  __shared__ int tmp[256];
  int i = blockIdx.x * 256 + threadIdx.x;
  int v = hist[i];
  tmp[threadIdx.x] = v;
  __syncthreads();
#pragma unroll
  for (int d = 1; d < 256; d <<= 1) {
    int t = (threadIdx.x >= d) ? tmp[threadIdx.x - d] : 0;
    __syncthreads();
    tmp[threadIdx.x] += t;
    __syncthreads();
  }
  offs[i] = tmp[threadIdx.x] - v;                 // exclusive within block
  if (threadIdx.x == 255) bsums[blockIdx.x] = tmp[255];
}

__global__ __launch_bounds__(256)
void scan2(const int* __restrict__ bsums, int* __restrict__ bpre,
           float* __restrict__ zstats) {
  // zero s1|s2|cnt (contiguous 8256 floats) — consumed by node_mlp later
  for (int i = threadIdx.x; i < 8256; i += 256) zstats[i] = 0.f;
  __shared__ int tmp[256];
  int v = (threadIdx.x < NB_SCAN) ? bsums[threadIdx.x] : 0;
  tmp[threadIdx.x] = v;
  __syncthreads();
#pragma unroll
  for (int d = 1; d < 256; d <<= 1) {
    int t = (threadIdx.x >= d) ? tmp[threadIdx.x - d] : 0;
    __syncthreads();
    tmp[threadIdx.x] += t;
    __syncthreads();
  }
  bpre[threadIdx.x] = tmp[threadIdx.x] - v;       // exclusive block prefix
}

__global__ __launch_bounds__(256)
void scatter_k(const int* __restrict__ ei, int* __restrict__ offs,
               const int* __restrict__ bpre, int* __restrict__ sorted) {
  int e = blockIdx.x * 256 + threadIdx.x;
  if (e >= N_EDGES) return;
  int d = ei[N_EDGES + e];
  int pos = atomicAdd(&offs[d], 1) + bpre[d >> 8];
  sorted[pos] = e;
}

// ---------------------------------------------------------------------------
// Edge MLP — block-cooperative, 64 dst-sorted edges / block.
// R17 = R16 + global_load_lds staging for h_dst/h_src (T-ladder's biggest
// lever, never applied here). h sections stored UNPADDED stride 64 shorts
// (128 B) as required (LDS dest = uniform base + lane*16); the 16-way read
// conflict that stride would cause is killed by pre-swizzled SOURCE chunks
// (global chunk = c^e) + XOR on the af read (^(col&7)) — m173 pattern.
// ea keeps reg-staged pack path into stride-40 section (2-way, free).
// Staging layout in buf (shorts): sA_d[64][64]@0, sA_s[64][64]@4096,
// sE[64][40]@8192 (10752 total); sH [64][264] aliases whole buf after b2.
// ---------------------------------------------------------------------------
#define LDH   264   // 256 + 8 pad shorts; row = 528 B (16B aligned)
#define LDC   68    // fp32 stride of C tile
#define SAS_OFF 4096
#define SE_OFF  8192
#define SE_LD   40

__global__ __launch_bounds__(256, 2)
void edge_mlp(const short* __restrict__ h_bf, const float* __restrict__ ea,
              const int* __restrict__ ei, const int* __restrict__ sorted,
              const short* __restrict__ w1f, const float* __restrict__ b1,
              const short* __restrict__ w2f, const float* __restrict__ b2,
              float* __restrict__ agg) {
  __shared__ __align__(16) short buf[64 * LDH];    // staging then sH (aliased)
  __shared__ __align__(16) float sC[64 * LDC];     // 17408 B
  __shared__ int s_ids[4][48];                     // src[16], dst[16], eid[16]

  const int tid  = threadIdx.x;
  const int lane = tid & 63;
  const int wave = tid >> 6;
  const int col  = lane & 15;
  const int quad = lane >> 4;
  const int eb   = blockIdx.x * 64 + wave * 16;    // this wave's 16 sorted slots
  short* sH = buf;

  // ---- resolve sorted edge ids -> src/dst/eid (wave-local)
  if (lane < 48) {
    int i15 = lane & 15;
    int e0 = sorted[eb + i15];
    int v;
    if (lane < 16)      v = ei[e0];
    else if (lane < 32) v = ei[N_EDGES + e0];
    else                v = e0;
    s_ids[wave][lane] = v;
  }

  // ---- stage h_dst | h_src rows via global_load_lds (async, no VGPR trip).
  // lane (e=lane>>3, c=lane&7) loads GLOBAL chunk c^e of its row -> LDS
  // linear (base + lane*16) => physical chunk p of row r holds logical p^(r&7).
  {
    const int e = lane >> 3, c = lane & 7;
#pragma unroll
    for (int it = 0; it < 2; ++it) {
      int d = s_ids[wave][16 + it * 8 + e];
      int s = s_ids[wave][it * 8 + e];
      const short* gd = h_bf + (size_t)d * 64 + (c ^ e) * 8;
      const short* gs = h_bf + (size_t)s * 64 + (c ^ e) * 8;
      gload_lds16(gd, &buf[(wave * 16 + it * 8) * 64]);
      gload_lds16(gs, &buf[SAS_OFF + (wave * 16 + it * 8) * 64]);
    }
  }
  // ---- stage edge_attr (fp32 -> packed bf16, reg path, stride-40 section)
#pragma unroll
  for (int it = 0; it < 2; ++it) {
    int idx = it * 64 + lane;        // 0..127
    int e = idx >> 3, j = idx & 7;
    int row = wave * 16 + e;
    int eid = s_ids[wave][32 + e];
    float4v v = *(const float4v*)(ea + (size_t)eid * 32 + j * 4);
    uint2v p = {pack_bf16x2(v.x, v.y), pack_bf16x2(v.z, v.w)};
    *(uint2v*)&buf[SE_OFF + row * SE_LD + j * 4] = p;
  }
  __syncthreads();                                  // b1: staging visible (drains vmcnt)

  // ---- GEMM1: [64,160] x [160,256]; wave covers n-tiles [4w, 4w+4)
  f32x4 acc[4][4];
#pragma unroll
  for (int mt = 0; mt < 4; ++mt)
#pragma unroll
    for (int nt = 0; nt < 4; ++nt)
      acc[mt][nt] = (f32x4){0.f, 0.f, 0.f, 0.f};

  short8 bf[2][4];
#pragma unroll
  for (int nt = 0; nt < 4; ++nt)
    bf[0][nt] = *(const short8*)(w1f + (size_t)((wave * 4 + nt) * 64 + lane) * 8);

#pragma unroll
  for (int kt = 0; kt < 5; ++kt) {
    if (kt < 4) {
#pragma unroll
      for (int nt = 0; nt < 4; ++nt)
        bf[(kt + 1) & 1][nt] = *(const short8*)(
            w1f + (size_t)(((kt + 1) * 16 + wave * 4 + nt) * 64 + lane) * 8);
    }
    short8 af[4];
#pragma unroll
    for (int mt = 0; mt < 4; ++mt) {
      const int row = mt * 16 + col;
      if (kt < 2)
        af[mt] = *(const short8*)&buf[row * 64 + (((kt * 4 + quad) ^ (col & 7)) * 8)];
      else if (kt < 4)
        af[mt] = *(const short8*)&buf[SAS_OFF + row * 64 +
                                      ((((kt - 2) * 4 + quad) ^ (col & 7)) * 8)];
      else
        af[mt] = *(const short8*)&buf[SE_OFF + row * SE_LD + quad * 8];
    }
    __builtin_amdgcn_s_setprio(1);
#pragma unroll
    for (int nt = 0; nt < 4; ++nt)
#pragma unroll
      for (int mt = 0; mt < 4; ++mt)
        acc[mt][nt] = mfma16(af[mt], bf[kt & 1][nt], acc[mt][nt]);
    __builtin_amdgcn_s_setprio(0);
  }

  // ---- hoist GEMM2's first weight fragment (L2 latency hides under silu)
  short8 bf2[2];
  bf2[0] = *(const short8*)(w2f + (size_t)(wave * 64 + lane) * 8);

  __syncthreads();                                  // b2: staging dead, reuse as sH

  // ---- bias + silu -> sH, permuted-hidden packed writes:
  // storage col ns = wave*64 + col*4 + nt  (4 consecutive shorts per lane)
  {
    float b1v[4];
#pragma unroll
    for (int nt = 0; nt < 4; ++nt) b1v[nt] = b1[(wave * 4 + nt) * 16 + col];
#pragma unroll
    for (int mt = 0; mt < 4; ++mt) {
#pragma unroll
      for (int r = 0; r < 4; ++r) {
        const int row = mt * 16 + quad * 4 + r;
        float v0 = silu_f(acc[mt][0][r] + b1v[0]);
        float v1 = silu_f(acc[mt][1][r] + b1v[1]);
        float v2 = silu_f(acc[mt][2][r] + b1v[2]);
        float v3 = silu_f(acc[mt][3][r] + b1v[3]);
        uint2v p = {cvt_pk_bf16(v0, v1), cvt_pk_bf16(v2, v3)};
        *(uint2v*)&sH[row * LDH + wave * 64 + col * 4] = p;
      }
    }
  }
  __syncthreads();                                  // b3: sH visible

  // ---- GEMM2: [64,256] x [256,64]; wave covers n-tile `wave` (16 cols)
  f32x4 acc2[4];
#pragma unroll
  for (int mt = 0; mt < 4; ++mt) acc2[mt] = (f32x4){0.f, 0.f, 0.f, 0.f};

#pragma unroll
  for (int kt = 0; kt < 8; ++kt) {
    if (kt < 7)
      bf2[(kt + 1) & 1] = *(const short8*)(
          w2f + (size_t)(((kt + 1) * 4 + wave) * 64 + lane) * 8);
    short8 af[4];
#pragma unroll
    for (int mt = 0; mt < 4; ++mt)
      af[mt] = *(const short8*)&sH[(mt * 16 + col) * LDH + kt * 32 + quad * 8];
    __builtin_amdgcn_s_setprio(1);
#pragma unroll
    for (int mt = 0; mt < 4; ++mt)
      acc2[mt] = mfma16(af[mt], bf2[kt & 1], acc2[mt]);
    __builtin_amdgcn_s_setprio(0);
  }

  // ---- dump C (+bias) into separate sC tile (no barrier needed before)
  {
    const int n = wave * 16 + col;
    const float bias = b2[n];
#pragma unroll
    for (int mt = 0; mt < 4; ++mt)
#pragma unroll
      for (int r = 0; r < 4; ++r)
        sC[(mt * 16 + quad * 4 + r) * LDC + n] = acc2[mt][r] + bias;
  }
  __syncthreads();                                  // b4: sC visible

  // ---- run-reduce own 16 contiguous rows (dst-sorted): one atomic per run
  {
    float sum = 0.f;
    int prev = s_ids[wave][16];
#pragma unroll
    for (int r = 0; r < 16; ++r) {
      float v = sC[(wave * 16 + r) * LDC + lane];
      int d = s_ids[wave][16 + r];          // LDS broadcast -> wave-uniform
      if (d != prev) {
        atomicAdd(agg + (size_t)prev * D_MODEL + lane, sum);
        sum = 0.f; prev = d;
      }
      sum += v;
    }
    atomicAdd(agg + (size_t)prev * D_MODEL + lane, sum);
  }
}

// ---------------------------------------------------------------------------
// Node MLP — block-cooperative, 64 nodes / block, fused GraphNorm stats.
// R17 = R14/R16 + global_load_lds for the h section (rows contiguous) with
// the same source-swizzle; agg keeps reg-staged pack path (stride-72, 2-way).
// Staging: sN_h[64][64]@0, sN_a[64][72]@4096 (8704 shorts); sH aliases buf.
// ---------------------------------------------------------------------------
#define NA_OFF 4096
#define NA_LD  72

__global__ __launch_bounds__(256, 2)
void node_mlp(const float* __restrict__ h, const short* __restrict__ h_bf,
              const float* __restrict__ agg,
              const short* __restrict__ w1f, const float* __restrict__ b1,
              const short* __restrict__ w2f, const float* __restrict__ b2,
              const int* __restrict__ batch,
              float* __restrict__ hnew,
              float* __restrict__ s1, float* __restrict__ s2,
              float* __restrict__ cnt) {
  __shared__ __align__(16) short buf[64 * LDH];    // staging then sH (aliased)
  __shared__ int s_b[64];                          // batch ids of block rows

  const int tid  = threadIdx.x;
  const int lane = tid & 63;
  const int wave = tid >> 6;
  const int col  = lane & 15;
  const int quad = lane >> 4;
  const int nb   = blockIdx.x * 64;
  short* sH = buf;

  if (tid < 64) {
    int gi = nb + tid;
    s_b[tid] = batch[(gi < N_NODES) ? gi : (N_NODES - 1)];
  }

  // ---- stage h rows via global_load_lds (source chunk pre-swizzle c^e)
  {
    const int e = lane >> 3, c = lane & 7;
#pragma unroll
    for (int it = 0; it < 2; ++it) {
      int gi = nb + wave * 16 + it * 8 + e;
      if (gi >= N_NODES) gi = N_NODES - 1;
      const short* g = h_bf + (size_t)gi * 64 + (c ^ e) * 8;
      gload_lds16(g, &buf[(wave * 16 + it * 8) * 64]);
    }
  }
  // ---- stage agg rows (fp32 -> packed bf16, reg path, stride-72 section)
#pragma unroll
  for (int it = 0; it < 4; ++it) {
    int idx = it * 64 + lane;     // 0..255
    int i = idx >> 4, j = idx & 15;
    int row = wave * 16 + i;
    int gi = nb + row;
    if (gi >= N_NODES) gi = N_NODES - 1;
    float4v v = *(const float4v*)(agg + (size_t)gi * D_MODEL + j * 4);
    uint2v p = {pack_bf16x2(v.x, v.y), pack_bf16x2(v.z, v.w)};
    *(uint2v*)&buf[NA_OFF + row * NA_LD + j * 4] = p;
  }
  __syncthreads();                                  // b1: staging + s_b visible

  // ---- per-graph node counts (one wave; ballot run-length over 64 rows)
  if (wave == 3) {
    int gi = nb + lane;
    bool valid = gi < N_NODES;
    int g = s_b[lane];
    int gp = __shfl_up(g, 1);
    bool start = valid && (lane == 0 || g != gp);
    unsigned long long bmask = __ballot(start);
    unsigned long long imask = __ballot(!valid);
    if (start) {
      unsigned long long higher =
          (lane == 63) ? 0ULL : (((bmask | imask) >> (lane + 1)) << (lane + 1));
      int next = higher ? (__ffsll((long long)higher) - 1) : 64;
      atomicAdd(&cnt[g], (float)(next - lane));
    }
  }

  // ---- GEMM1: K=128 (h | agg); wave covers n-tiles [4w, 4w+4)
  f32x4 acc[4][4];
#pragma unroll
  for (int mt = 0; mt < 4; ++mt)
#pragma unroll
    for (int nt = 0; nt < 4; ++nt)
      acc[mt][nt] = (f32x4){0.f, 0.f, 0.f, 0.f};

  short8 bf[2][4];
#pragma unroll
  for (int nt = 0; nt < 4; ++nt)
    bf[0][nt] = *(const short8*)(w1f + (size_t)((wave * 4 + nt) * 64 + lane) * 8);

#pragma unroll
  for (int kt = 0; kt < 4; ++kt) {
    if (kt < 3) {
#pragma unroll
      for (int nt = 0; nt < 4; ++nt)
        bf[(kt + 1) & 1][nt] = *(const short8*)(
            w1f + (size_t)(((kt + 1) * 16 + wave * 4 + nt) * 64 + lane) * 8);
    }
    short8 af[4];
#pragma unroll
    for (int mt = 0; mt < 4; ++mt) {
      const int row = mt * 16 + col;
      if (kt < 2)
        af[mt] = *(const short8*)&buf[row * 64 + (((kt * 4 + quad) ^ (col & 7)) * 8)];
      else
        af[mt] = *(const short8*)&buf[NA_OFF + row * NA_LD + (kt - 2) * 32 + quad * 8];
    }
    __builtin_amdgcn_s_setprio(1);
#pragma unroll
    for (int nt = 0; nt < 4; ++nt)
#pragma unroll
      for (int mt = 0; mt < 4; ++mt)
        acc[mt][nt] = mfma16(af[mt], bf[kt & 1][nt], acc[mt][nt]);
    __builtin_amdgcn_s_setprio(0);
  }

  // ---- hoist GEMM2's first weight fragment
  short8 bf2[2];
  bf2[0] = *(const short8*)(w2f + (size_t)(wave * 64 + lane) * 8);

  __syncthreads();                                  // b2: staging dead

  // ---- bias + silu -> sH, permuted-hidden packed writes (matches u2f perm)
  {
    float b1v[4];
#pragma unroll
    for (int nt = 0; nt < 4; ++nt) b1v[nt] = b1[(wave * 4 + nt) * 16 + col];
#pragma unroll
    for (int mt = 0; mt < 4; ++mt) {
#pragma unroll
      for (int r = 0; r < 4; ++r) {
        const int row = mt * 16 + quad * 4 + r;
        float v0 = silu_f(acc[mt][0][r] + b1v[0]);
        float v1 = silu_f(acc[mt][1][r] + b1v[1]);
        float v2 = silu_f(acc[mt][2][r] + b1v[2]);
        float v3 = silu_f(acc[mt][3][r] + b1v[3]);
        uint2v p = {cvt_pk_bf16(v0, v1), cvt_pk_bf16(v2, v3)};
        *(uint2v*)&sH[row * LDH + wave * 64 + col * 4] = p;
      }
    }
  }
  __syncthreads();                                  // b3: sH visible

  // ---- GEMM2: K=256; wave covers n-tile `wave`
  f32x4 acc2[4];
#pragma unroll
  for (int mt = 0; mt < 4; ++mt) acc2[mt] = (f32x4){0.f, 0.f, 0.f, 0.f};

#pragma unroll
  for (int kt = 0; kt < 8; ++kt) {
    if (kt < 7)
      bf2[(kt + 1) & 1] = *(const short8*)(
          w2f + (size_t)(((kt + 1) * 4 + wave) * 64 + lane) * 8);
    short8 af[4];
#pragma unroll
    for (int mt = 0; mt < 4; ++mt)
      af[mt] = *(const short8*)&sH[(mt * 16 + col) * LDH + kt * 32 + quad * 8];
    __builtin_amdgcn_s_setprio(1);
#pragma unroll
    for (int mt = 0; mt < 4; ++mt)
      acc2[mt] = mfma16(af[mt], bf2[kt & 1], acc2[mt]);
    __builtin_amdgcn_s_setprio(0);
  }

  // ---- epilogue: h_new = h + dh -> global + GraphNorm stat accumulation.
  {
    const int n = wave * 16 + col;
    const float bias = b2[n];
    const bool uni = (nb + 64 <= N_NODES) && (s_b[0] == s_b[63]);
    if (uni) {
      // fast path (~92% of blocks): whole block one graph, all rows valid
      const int g = s_b[0];
      float a1 = 0.f, a2 = 0.f;
#pragma unroll
      for (int mt = 0; mt < 4; ++mt) {
#pragma unroll
        for (int r = 0; r < 4; ++r) {
          const int gi = nb + mt * 16 + quad * 4 + r;
          float hv = h[(size_t)gi * D_MODEL + n] + acc2[mt][r] + bias;
          hnew[(size_t)gi * D_MODEL + n] = hv;
          a1 += hv; a2 += hv * hv;
        }
      }
      a1 += __shfl_xor(a1, 16); a1 += __shfl_xor(a1, 32);
      a2 += __shfl_xor(a2, 16); a2 += __shfl_xor(a2, 32);
      if (quad == 0) {
        atomicAdd(&s1[g * D_MODEL + n], a1);
        atomicAdd(&s2[g * D_MODEL + n], a2);
      }
    } else {
      float a1 = 0.f, a2 = 0.f;
      int prev = s_b[quad * 4];     // lane's first row (mt=0, r=0)
#pragma unroll
      for (int mt = 0; mt < 4; ++mt) {
#pragma unroll
        for (int r = 0; r < 4; ++r) {
          const int row = mt * 16 + quad * 4 + r;
          const int gi = nb + row;
          const bool valid = gi < N_NODES;
          int g = s_b[row];
          if (g != prev) {
            atomicAdd(&s1[prev * D_MODEL + n], a1);
            atomicAdd(&s2[prev * D_MODEL + n], a2);
            a1 = 0.f; a2 = 0.f; prev = g;
          }
          if (valid) {
            float hv = h[(size_t)gi * D_MODEL + n] + acc2[mt][r] + bias;
            hnew[(size_t)gi * D_MODEL + n] = hv;
            a1 += hv; a2 += hv * hv;
          }
        }
      }
      atomicAdd(&s1[prev * D_MODEL + n], a1);
      atomicAdd(&s2[prev * D_MODEL + n], a2);
    }
  }
}

// ---------------------------------------------------------------------------
// GraphNorm normalize (stats already produced by node_mlp).
// ---------------------------------------------------------------------------
__global__ __launch_bounds__(256)
void gn_norm(float* __restrict__ x, const int* __restrict__ batch,
             const float* __restrict__ s1, const float* __restrict__ s2,
             const float* __restrict__ cnt, const float* __restrict__ alpha,
             const float* __restrict__ weight, const float* __restrict__ bias) {
  int idx = blockIdx.x * 256 + threadIdx.x;
  if (idx >= N_NODES * D_MODEL) return;
  int i = idx >> 6, f = idx & 63;
  int g = batch[i];
  float c = fmaxf(cnt[g], 1.f);
  float m   = s1[g * D_MODEL + f] / c;
  float ex2 = s2[g * D_MODEL + f] / c;
  float a = alpha[f];
  float var = ex2 - 2.f * a * m * m + a * a * m * m;
  float hc = x[idx] - a * m;
  x[idx] = weight[f] * hc * rsqrtf(var + EPS_GN) + bias[f];
}

// ---------------------------------------------------------------------------
extern "C" void kernel_launch(void* const* d_in, const int* in_sizes, int n_in,
                              void* d_out, int out_size, void* d_ws, size_t ws_size,
                              hipStream_t stream) {
  const float* h     = (const float*)d_in[0];
  const float* ea    = (const float*)d_in[1];
  const int*   ei    = (const int*)d_in[2];   // [2][E], row0=src, row1=dst
  const int*   batch = (const int*)d_in[3];
  const float* mw1   = (const float*)d_in[4];
  const float* mb1   = (const float*)d_in[5];
  const float* mw2   = (const float*)d_in[6];
  const float* mb2   = (const float*)d_in[7];
  const float* uw1   = (const float*)d_in[8];
  const float* ub1   = (const float*)d_in[9];
  const float* uw2   = (const float*)d_in[10];
  const float* ub2   = (const float*)d_in[11];
  const float* gw    = (const float*)d_in[12];
  const float* gb    = (const float*)d_in[13];
  const float* ga    = (const float*)d_in[14];

  char* ws = (char*)d_ws;
  float* agg    = (float*)(ws + 0);             // 12,800,000 B
  short* w1f    = (short*)(ws + 12800000);      //     81,920 B
  short* w2f    = (short*)(ws + 12881920);      //     32,768 B
  short* u1f    = (short*)(ws + 12914688);      //     65,536 B
  short* u2f    = (short*)(ws + 12980224);      //     32,768 B
  float* s1     = (float*)(ws + 13012992);      //     16,384 B
  float* s2     = (float*)(ws + 13029376);      //     16,384 B
  float* cnt    = (float*)(ws + 13045760);      //        256 B
  int*   hist   = (int*)  (ws + 13046016);      //    200,704 B (50176 ints)
  int*   offs   = (int*)  (ws + 13246720);      //    200,704 B
  int*   bsums  = (int*)  (ws + 13447424);      //      1,024 B
  int*   bpre   = (int*)  (ws + 13448448);      //      1,024 B
  int*   sorted = (int*)  (ws + 13449472);      //  3,200,000 B
  short* h_bf   = (short*)(ws + 16649472);      //  6,400,000 B -> end 23,049,472

  float* zstats = (float*)(ws + 13012992);      // s1|s2|cnt contiguous (8256 f)

  // weights (52) + hist-zero (196) + h_bf (1563)
  prep_all<<<52 + 196 + HBF_BLOCKS, 256, 0, stream>>>(mw1, mw2, uw1, uw2, h,
                                                      w1f, w2f, u1f, u2f,
                                                      h_bf, hist);

  // counting sort of edges by dst (hist_k also zeroes agg)
  hist_k  <<<(N_EDGES + 255) / 256, 256, 0, stream>>>(ei, hist, agg);
  scan1   <<<NB_SCAN, 256, 0, stream>>>(hist, offs, bsums);
  scan2   <<<1, 256, 0, stream>>>(bsums, bpre, zstats);
  scatter_k<<<(N_EDGES + 255) / 256, 256, 0, stream>>>(ei, offs, bpre, sorted);

  edge_mlp<<<N_EDGES / 64, 256, 0, stream>>>(h_bf, ea, ei, sorted,
                                             w1f, mb1, w2f, mb2, agg);

  node_mlp<<<(N_NODES + 63) / 64, 256, 0, stream>>>(h, h_bf, agg,
                                                    u1f, ub1, u2f, ub2,
                                                    batch, (float*)d_out,
                                                    s1, s2, cnt);

  gn_norm<<<(N_NODES * D_MODEL + 255) / 256, 256, 0, stream>>>(
      (float*)d_out, batch, s1, s2, cnt, ga, gw, gb);
}